// Round 6
// baseline (312.749 us; speedup 1.0000x reference)
//
#include <hip/hip_runtime.h>
#include <hip/hip_bf16.h>
#include <math.h>

#define EPT 16      // edges per thread in scatter kernel
#define BCAP 16384  // bucket capacity (avg ~8.2k for uniform random, +90 sigma)

typedef __bf16 bf16x8 __attribute__((ext_vector_type(8)));
typedef float f32x4 __attribute__((ext_vector_type(4)));

__device__ __forceinline__ unsigned short bf16r(float f) {
    unsigned u = __builtin_bit_cast(unsigned, f);
    unsigned r = (u + 0x7fffu + ((u >> 16) & 1u)) >> 16;
    return (unsigned short)r;
}
__device__ __forceinline__ float bf_lo(unsigned u) {
    return __builtin_bit_cast(float, u << 16);
}
__device__ __forceinline__ float bf_hi(unsigned u) {
    return __builtin_bit_cast(float, u & 0xffff0000u);
}

// ---------------- CSR build: single-pass 512-node bucket binning ----------------
// bucket b = dst >> 9; edge record = (src << 9) | (dst & 511)  [needs N <= 131072]

__global__ void scat1_kernel(const int* __restrict__ src, const int* __restrict__ dst,
                             int* __restrict__ cntg, unsigned* __restrict__ ebuf, int E) {
    __shared__ int lh[256];
    __shared__ int lbase[256];
    int tid = threadIdx.x;
    lh[tid] = 0;
    __syncthreads();
    int base = blockIdx.x * (256 * EPT);
    for (int k = 0; k < EPT; ++k) {
        int e = base + k * 256 + tid;
        if (e < E) atomicAdd(&lh[dst[e] >> 9], 1);
    }
    __syncthreads();
    if (lh[tid] > 0) lbase[tid] = atomicAdd(&cntg[tid], lh[tid]);
    lh[tid] = 0;
    __syncthreads();
    for (int k = 0; k < EPT; ++k) {
        int e = base + k * 256 + tid;
        if (e < E) {
            int s = src[e], d = dst[e];
            int b = d >> 9;
            int pos = lbase[b] + atomicAdd(&lh[b], 1);
            ebuf[(size_t)b * BCAP + pos] = ((unsigned)s << 9) | (unsigned)(d & 511);
        }
    }
}

// exclusive scan of the 256 bucket counts -> global CSR bucket offsets
__global__ void bscan_kernel(const int* __restrict__ cntg, int* __restrict__ bstart) {
    __shared__ int sh[256];
    int tid = threadIdx.x;
    int v = cntg[tid];
    sh[tid] = v;
    __syncthreads();
    int val = v;
    for (int off = 1; off < 256; off <<= 1) {
        int add = 0;
        if (tid >= off) add = sh[tid - off];
        __syncthreads();
        val += add;
        sh[tid] = val;
        __syncthreads();
    }
    bstart[tid] = val - v;
    if (tid == 255) bstart[256] = val;
}

// one block per bucket: local degrees -> scan -> row_ptr/dinv -> fine scatter
__global__ void build_kernel(const unsigned* __restrict__ ebuf, const int* __restrict__ cntg,
                             const int* __restrict__ bstart, int* __restrict__ row_ptr,
                             int* __restrict__ col, float* __restrict__ dinv, int N, int E) {
    __shared__ int deg[512];
    __shared__ int sh[256];
    int b = blockIdx.x;
    int tid = threadIdx.x;
    int nodeBase = b << 9;
    int nn = N - nodeBase;
    if (nn > 512) nn = 512;
    if (nn < 0) nn = 0;
    const unsigned* eb = ebuf + (size_t)b * BCAP;
    int cnt = cntg[b];
    int start = bstart[b];

    deg[tid] = 0;
    deg[tid + 256] = 0;
    __syncthreads();
    for (int j = tid; j < cnt; j += 256) {
        atomicAdd(&deg[eb[j] & 511u], 1);
    }
    __syncthreads();

    int i0 = tid * 2, i1 = i0 + 1;
    int v0 = deg[i0], v1 = deg[i1];
    int tot = v0 + v1;
    sh[tid] = tot;
    __syncthreads();
    int val = tot;
    for (int off = 1; off < 256; off <<= 1) {
        int add = 0;
        if (tid >= off) add = sh[tid - off];
        __syncthreads();
        val += add;
        sh[tid] = val;
        __syncthreads();
    }
    int excl = val - tot;

    if (i0 < nn) { row_ptr[nodeBase + i0] = start + excl;      dinv[nodeBase + i0] = rsqrtf((float)v0 + 1.0f); }
    if (i1 < nn) { row_ptr[nodeBase + i1] = start + excl + v0; dinv[nodeBase + i1] = rsqrtf((float)v1 + 1.0f); }
    if (b == 0 && tid == 0) row_ptr[N] = E;
    // repurpose deg[] as absolute write cursors
    deg[i0] = start + excl;
    deg[i1] = start + excl + v0;
    __syncthreads();

    for (int j = tid; j < cnt; j += 256) {
        unsigned rec = eb[j];
        int pos = atomicAdd(&deg[rec & 511u], 1);
        col[pos] = (int)(rec >> 9);
    }
}

// ---------------- fp32 -> bf16 feature convert ----------------

__global__ void cvt_kernel(const float* __restrict__ x, unsigned short* __restrict__ xb,
                           int n4) {
    int i = blockIdx.x * 256 + threadIdx.x;
    if (i < n4) {
        float4 v = *(const float4*)(x + (size_t)i * 4);
        ushort4 o;
        o.x = bf16r(v.x); o.y = bf16r(v.y); o.z = bf16r(v.z); o.w = bf16r(v.w);
        *(ushort4*)(xb + (size_t)i * 4) = o;
    }
}

// ---------------- weight pack: W -> MFMA B-fragment order, bf16 ----------------
// layout: wp[t*1024 + h*512 + lane*8 + j] = W[h*32 + (lane>>4)*8 + j][t*16 + (lane&15)]

__global__ void pack_kernel(const float* __restrict__ W1, const float* __restrict__ Wh,
                            const float* __restrict__ W2, unsigned short* __restrict__ wp1,
                            unsigned short* __restrict__ wph, unsigned short* __restrict__ wp2) {
    int i = blockIdx.x * 256 + threadIdx.x;   // grid 16 -> i in [0,4096)
    int j = i & 7;
    int lane = (i >> 3) & 63;
    int hh = (i >> 9) & 1;
    int t = i >> 10;
    int k = hh * 32 + (lane >> 4) * 8 + j;
    int cc = t * 16 + (lane & 15);
    wp1[i] = bf16r(W1[k * 64 + cc]);
    wph[i] = bf16r(Wh[k * 64 + cc]);
    if (t < 3) wp2[i] = bf16r(cc < 40 ? W2[k * 40 + cc] : 0.f);
}

// ---------------- aggregation: agg[node] = di*( sum dinv[s]*h[s] + di*h[node] ) ----
// One wave per node: lane = edge-slot(3b) x channel-oct(3b). Per 64-edge chunk:
// statically-unrolled 8 sub-blocks guarded by wave-uniform (i*8 < cnt), so all
// shfls issue together, then up to 8 uint4 loads back-to-back (deep MLP), then
// the FMAs. Tail lanes carry dw=0 from the prefetch, so loads need no per-lane
// masks (idx defaults to `node` -> always a valid row).

__launch_bounds__(256, 6)
__global__ void agg_kernel(const unsigned short* __restrict__ h, const int* __restrict__ row_ptr,
                           const int* __restrict__ col, const float* __restrict__ dinv,
                           unsigned short* __restrict__ aggout, int n) {
    int tid = threadIdx.x;
    int lane = tid & 63;
    int node = blockIdx.x * 4 + (tid >> 6);
    if (node >= n) return;

    int sub = lane >> 3;        // edge slot 0..7
    int ch8 = (lane & 7) * 8;   // channel base

    int beg = row_ptr[node];
    int deg = row_ptr[node + 1] - beg;
    float di = dinv[node];
    int total = deg + 1;        // + virtual self edge (weight di)

    float acc[8];
#pragma unroll
    for (int j = 0; j < 8; ++j) acc[j] = 0.f;

    int base = 0;
    while (base < total) {
        int vi = base + lane;
        int idx = node;
        float dw = 0.f;
        if (vi < deg) {
            idx = col[beg + vi];
            dw = dinv[idx];
        } else if (vi == deg) {
            dw = di;            // self edge
        }
        int cnt = min(total - base, 64);

        int s[8];
        float d[8];
        uint4 u[8];
#pragma unroll
        for (int i = 0; i < 8; ++i) {
            if (i * 8 < cnt) {
                int e = i * 8 + sub;
                s[i] = __shfl(idx, e);
                d[i] = __shfl(dw, e);
            }
        }
#pragma unroll
        for (int i = 0; i < 8; ++i) {
            if (i * 8 < cnt)
                u[i] = *(const uint4*)(h + (size_t)s[i] * 64 + ch8);
        }
#pragma unroll
        for (int i = 0; i < 8; ++i) {
            if (i * 8 < cnt) {
                acc[0] += d[i] * bf_lo(u[i].x); acc[1] += d[i] * bf_hi(u[i].x);
                acc[2] += d[i] * bf_lo(u[i].y); acc[3] += d[i] * bf_hi(u[i].y);
                acc[4] += d[i] * bf_lo(u[i].z); acc[5] += d[i] * bf_hi(u[i].z);
                acc[6] += d[i] * bf_lo(u[i].w); acc[7] += d[i] * bf_hi(u[i].w);
            }
        }
        base += cnt;
    }
    // reduce the 8 edge slots (lane bits 3,4,5)
#pragma unroll
    for (int off = 8; off <= 32; off <<= 1) {
#pragma unroll
        for (int j = 0; j < 8; ++j) acc[j] += __shfl_xor(acc[j], off);
    }

    if (sub == 0) {
        unsigned p0 = (unsigned)bf16r(di * acc[0]) | ((unsigned)bf16r(di * acc[1]) << 16);
        unsigned p1 = (unsigned)bf16r(di * acc[2]) | ((unsigned)bf16r(di * acc[3]) << 16);
        unsigned p2 = (unsigned)bf16r(di * acc[4]) | ((unsigned)bf16r(di * acc[5]) << 16);
        unsigned p3 = (unsigned)bf16r(di * acc[6]) | ((unsigned)bf16r(di * acc[7]) << 16);
        *(uint4*)(aggout + (size_t)node * 64 + ch8) = make_uint4(p0, p1, p2, p3);
    }
}

// ---------------- MFMA epilogue GEMMs ----------------
// One wave per 16-node tile. A-frag: A[m=lane&15][k=quad*8+j] -> contiguous
// uint4 from agg buffer. B-frag from pre-packed wp. C/D: col=lane&15,
// row=quad*4+reg.

__global__ void gemm_relu_kernel(const unsigned short* __restrict__ A,
                                 const unsigned short* __restrict__ wp,
                                 const float* __restrict__ bias,
                                 unsigned short* __restrict__ out, int nTiles, int n) {
    int wv = blockIdx.x * 4 + (threadIdx.x >> 6);
    int lane = threadIdx.x & 63;
    if (wv >= nTiles) return;
    int q = lane >> 4, c = lane & 15;

    bf16x8 bfrag[4][2];
#pragma unroll
    for (int t = 0; t < 4; ++t)
#pragma unroll
        for (int hh = 0; hh < 2; ++hh)
            bfrag[t][hh] = *(const bf16x8*)(wp + t * 1024 + hh * 512 + lane * 8);
    float bs[4];
#pragma unroll
    for (int t = 0; t < 4; ++t) bs[t] = bias[t * 16 + c];

    int nodeBase = wv * 16;
    const unsigned short* arow = A + (size_t)(nodeBase + c) * 64 + q * 8;
    bf16x8 a0 = *(const bf16x8*)(arow);
    bf16x8 a1 = *(const bf16x8*)(arow + 32);

    f32x4 acc[4];
#pragma unroll
    for (int t = 0; t < 4; ++t) {
        f32x4 z = {0.f, 0.f, 0.f, 0.f};
        z = __builtin_amdgcn_mfma_f32_16x16x32_bf16(a0, bfrag[t][0], z, 0, 0, 0);
        z = __builtin_amdgcn_mfma_f32_16x16x32_bf16(a1, bfrag[t][1], z, 0, 0, 0);
        acc[t] = z;
    }

#pragma unroll
    for (int r = 0; r < 4; ++r) {
        int node = nodeBase + q * 4 + r;
        if (node < n) {
            unsigned short* orow = out + (size_t)node * 64;
#pragma unroll
            for (int t = 0; t < 4; ++t)
                orow[t * 16 + c] = bf16r(fmaxf(acc[t][r] + bs[t], 0.f));
        }
    }
}

__global__ void gemm_lsm_kernel(const unsigned short* __restrict__ A,
                                const unsigned short* __restrict__ wp,
                                const float* __restrict__ bias,
                                float* __restrict__ out, int nTiles, int n) {
    int wv = blockIdx.x * 4 + (threadIdx.x >> 6);
    int lane = threadIdx.x & 63;
    if (wv >= nTiles) return;
    int q = lane >> 4, c = lane & 15;
    bool v2ok = (c < 8);   // col 32+c < 40

    bf16x8 bfrag[3][2];
#pragma unroll
    for (int t = 0; t < 3; ++t)
#pragma unroll
        for (int hh = 0; hh < 2; ++hh)
            bfrag[t][hh] = *(const bf16x8*)(wp + t * 1024 + hh * 512 + lane * 8);
    float bs[3];
    bs[0] = bias[c];
    bs[1] = bias[16 + c];
    bs[2] = v2ok ? bias[32 + c] : 0.f;

    int nodeBase = wv * 16;
    const unsigned short* arow = A + (size_t)(nodeBase + c) * 64 + q * 8;
    bf16x8 a0 = *(const bf16x8*)(arow);
    bf16x8 a1 = *(const bf16x8*)(arow + 32);

    f32x4 acc[3];
#pragma unroll
    for (int t = 0; t < 3; ++t) {
        f32x4 z = {0.f, 0.f, 0.f, 0.f};
        z = __builtin_amdgcn_mfma_f32_16x16x32_bf16(a0, bfrag[t][0], z, 0, 0, 0);
        z = __builtin_amdgcn_mfma_f32_16x16x32_bf16(a1, bfrag[t][1], z, 0, 0, 0);
        acc[t] = z;
    }

#pragma unroll
    for (int r = 0; r < 4; ++r) {
        int node = nodeBase + q * 4 + r;
        if (node < n) {
            float v0 = acc[0][r] + bs[0];
            float v1 = acc[1][r] + bs[1];
            float v2 = v2ok ? (acc[2][r] + bs[2]) : -INFINITY;
            float m = fmaxf(fmaxf(v0, v1), v2);
#pragma unroll
            for (int off = 1; off <= 8; off <<= 1) m = fmaxf(m, __shfl_xor(m, off));
            float s = expf(v0 - m) + expf(v1 - m) + (v2ok ? expf(v2 - m) : 0.f);
#pragma unroll
            for (int off = 1; off <= 8; off <<= 1) s += __shfl_xor(s, off);
            float ls = m + logf(s);
            float* orow = out + (size_t)node * 40;
            orow[c] = v0 - ls;
            orow[16 + c] = v1 - ls;
            if (v2ok) orow[32 + c] = v2 - ls;
        }
    }
}

// ---------------- launch ----------------

extern "C" void kernel_launch(void* const* d_in, const int* in_sizes, int n_in,
                              void* d_out, int out_size, void* d_ws, size_t ws_size,
                              hipStream_t stream) {
    const float* x  = (const float*)d_in[0];
    const int* ei   = (const int*)d_in[1];
    const float* W1 = (const float*)d_in[2];
    const float* b1 = (const float*)d_in[3];
    const float* Wh = (const float*)d_in[4];
    const float* bh = (const float*)d_in[5];
    const float* W2 = (const float*)d_in[6];
    const float* b2 = (const float*)d_in[7];
    float* out = (float*)d_out;

    const int N = in_sizes[0] / 64;
    const int E = in_sizes[1] / 2;
    const int nbuk = (N + 511) >> 9;         // 512-node buckets (needs N <= 131072)
    const int nTiles = (N + 15) / 16;
    const int Npad = nTiles * 16;

    const int* srcp = ei;
    const int* dstp = ei + E;

    size_t off = 0;
    auto alloc = [&](size_t bytes) {
        size_t o = off;
        off = (off + bytes + 255) & ~(size_t)255;
        return o;
    };
    char* ws = (char*)d_ws;
    int*      cntg    = (int*)(ws + alloc(256 * 4));
    int*      bstart  = (int*)(ws + alloc(257 * 4));
    int*      row_ptr = (int*)(ws + alloc((size_t)(N + 1) * 4));
    float*    dinv    = (float*)(ws + alloc((size_t)N * 4));
    int*      col     = (int*)(ws + alloc((size_t)E * 4));
    unsigned* ebuf    = (unsigned*)(ws + alloc((size_t)nbuk * BCAP * 4));
    unsigned short* wp1  = (unsigned short*)(ws + alloc(4096 * 2));
    unsigned short* wph  = (unsigned short*)(ws + alloc(4096 * 2));
    unsigned short* wp2  = (unsigned short*)(ws + alloc(3072 * 2));
    unsigned short* xb   = (unsigned short*)(ws + alloc((size_t)Npad * 64 * 2));
    unsigned short* aggA = (unsigned short*)(ws + alloc((size_t)Npad * 64 * 2));
    unsigned short* gA   = (unsigned short*)(ws + alloc((size_t)Npad * 64 * 2));
    (void)ws_size;

    hipMemsetAsync(cntg, 0, 256 * 4, stream);

    const int ebGrid = (E + 256 * EPT - 1) / (256 * EPT);
    scat1_kernel<<<ebGrid, 256, 0, stream>>>(srcp, dstp, cntg, ebuf, E);
    bscan_kernel<<<1, 256, 0, stream>>>(cntg, bstart);
    build_kernel<<<nbuk, 256, 0, stream>>>(ebuf, cntg, bstart, row_ptr, col, dinv, N, E);

    cvt_kernel<<<(N * 64 / 4 + 255) / 256, 256, 0, stream>>>(x, xb, N * 64 / 4);
    pack_kernel<<<16, 256, 0, stream>>>(W1, Wh, W2, wp1, wph, wp2);

    const int aggGrid = (N + 3) / 4;
    const int gemmGrid = (nTiles + 3) / 4;

    // layer 1
    agg_kernel<<<aggGrid, 256, 0, stream>>>(xb, row_ptr, col, dinv, aggA, N);
    gemm_relu_kernel<<<gemmGrid, 256, 0, stream>>>(aggA, wp1, b1, gA, nTiles, N);
    // layer 2
    agg_kernel<<<aggGrid, 256, 0, stream>>>(gA, row_ptr, col, dinv, aggA, N);
    gemm_relu_kernel<<<gemmGrid, 256, 0, stream>>>(aggA, wph, bh, gA, nTiles, N);
    // layer 3
    agg_kernel<<<aggGrid, 256, 0, stream>>>(gA, row_ptr, col, dinv, aggA, N);
    gemm_lsm_kernel<<<gemmGrid, 256, 0, stream>>>(aggA, wp2, b2, out, nTiles, N);
}

// Round 7
// 301.946 us; speedup vs baseline: 1.0358x; 1.0358x over previous
//
#include <hip/hip_runtime.h>
#include <hip/hip_bf16.h>
#include <math.h>

#define EPT 16      // edges per thread in scatter kernel
#define BCAP 16384  // bucket capacity (avg ~8.2k for uniform random, +90 sigma)

typedef __bf16 bf16x8 __attribute__((ext_vector_type(8)));
typedef float f32x4 __attribute__((ext_vector_type(4)));

__device__ __forceinline__ unsigned short bf16r(float f) {
    unsigned u = __builtin_bit_cast(unsigned, f);
    unsigned r = (u + 0x7fffu + ((u >> 16) & 1u)) >> 16;
    return (unsigned short)r;
}
__device__ __forceinline__ float bf_lo(unsigned u) {
    return __builtin_bit_cast(float, u << 16);
}
__device__ __forceinline__ float bf_hi(unsigned u) {
    return __builtin_bit_cast(float, u & 0xffff0000u);
}

// ---------------- CSR build: single-pass 512-node bucket binning ----------------
// bucket b = dst >> 9; edge record = (src << 9) | (dst & 511)  [needs N <= 131072]

__global__ void scat1_kernel(const int* __restrict__ src, const int* __restrict__ dst,
                             int* __restrict__ cntg, unsigned* __restrict__ ebuf, int E) {
    __shared__ int lh[256];
    __shared__ int lbase[256];
    int tid = threadIdx.x;
    lh[tid] = 0;
    __syncthreads();
    int base = blockIdx.x * (256 * EPT);
    for (int k = 0; k < EPT; ++k) {
        int e = base + k * 256 + tid;
        if (e < E) atomicAdd(&lh[dst[e] >> 9], 1);
    }
    __syncthreads();
    if (lh[tid] > 0) lbase[tid] = atomicAdd(&cntg[tid], lh[tid]);
    lh[tid] = 0;
    __syncthreads();
    for (int k = 0; k < EPT; ++k) {
        int e = base + k * 256 + tid;
        if (e < E) {
            int s = src[e], d = dst[e];
            int b = d >> 9;
            int pos = lbase[b] + atomicAdd(&lh[b], 1);
            ebuf[(size_t)b * BCAP + pos] = ((unsigned)s << 9) | (unsigned)(d & 511);
        }
    }
}

// exclusive scan of the 256 bucket counts -> global CSR bucket offsets
__global__ void bscan_kernel(const int* __restrict__ cntg, int* __restrict__ bstart) {
    __shared__ int sh[256];
    int tid = threadIdx.x;
    int v = cntg[tid];
    sh[tid] = v;
    __syncthreads();
    int val = v;
    for (int off = 1; off < 256; off <<= 1) {
        int add = 0;
        if (tid >= off) add = sh[tid - off];
        __syncthreads();
        val += add;
        sh[tid] = val;
        __syncthreads();
    }
    bstart[tid] = val - v;
    if (tid == 255) bstart[256] = val;
}

// one block per bucket: local degrees -> scan -> row_ptr/dinv -> fine scatter
__global__ void build_kernel(const unsigned* __restrict__ ebuf, const int* __restrict__ cntg,
                             const int* __restrict__ bstart, int* __restrict__ row_ptr,
                             int* __restrict__ col, float* __restrict__ dinv, int N, int E) {
    __shared__ int deg[512];
    __shared__ int sh[256];
    int b = blockIdx.x;
    int tid = threadIdx.x;
    int nodeBase = b << 9;
    int nn = N - nodeBase;
    if (nn > 512) nn = 512;
    if (nn < 0) nn = 0;
    const unsigned* eb = ebuf + (size_t)b * BCAP;
    int cnt = cntg[b];
    int start = bstart[b];

    deg[tid] = 0;
    deg[tid + 256] = 0;
    __syncthreads();
    for (int j = tid; j < cnt; j += 256) {
        atomicAdd(&deg[eb[j] & 511u], 1);
    }
    __syncthreads();

    int i0 = tid * 2, i1 = i0 + 1;
    int v0 = deg[i0], v1 = deg[i1];
    int tot = v0 + v1;
    sh[tid] = tot;
    __syncthreads();
    int val = tot;
    for (int off = 1; off < 256; off <<= 1) {
        int add = 0;
        if (tid >= off) add = sh[tid - off];
        __syncthreads();
        val += add;
        sh[tid] = val;
        __syncthreads();
    }
    int excl = val - tot;

    if (i0 < nn) { row_ptr[nodeBase + i0] = start + excl;      dinv[nodeBase + i0] = rsqrtf((float)v0 + 1.0f); }
    if (i1 < nn) { row_ptr[nodeBase + i1] = start + excl + v0; dinv[nodeBase + i1] = rsqrtf((float)v1 + 1.0f); }
    if (b == 0 && tid == 0) row_ptr[N] = E;
    // repurpose deg[] as absolute write cursors
    deg[i0] = start + excl;
    deg[i1] = start + excl + v0;
    __syncthreads();

    for (int j = tid; j < cnt; j += 256) {
        unsigned rec = eb[j];
        int pos = atomicAdd(&deg[rec & 511u], 1);
        col[pos] = (int)(rec >> 9);
    }
}

// ---------------- fused convert + weight pack ----------------
// blocks [0,16): pack W1/Wh/W2 into MFMA B-fragment order (bf16):
//   wp[t*1024 + h*512 + lane*8 + j] = W[h*32 + (lane>>4)*8 + j][t*16 + (lane&15)]
// blocks [16, ...): fp32 -> bf16 convert of x.

__global__ void cvtpack_kernel(const float* __restrict__ x, unsigned short* __restrict__ xb,
                               int n4, const float* __restrict__ W1, const float* __restrict__ Wh,
                               const float* __restrict__ W2, unsigned short* __restrict__ wp1,
                               unsigned short* __restrict__ wph, unsigned short* __restrict__ wp2) {
    int bid = blockIdx.x;
    if (bid < 16) {
        int i = bid * 256 + threadIdx.x;   // i in [0,4096)
        int j = i & 7;
        int lane = (i >> 3) & 63;
        int hh = (i >> 9) & 1;
        int t = i >> 10;
        int k = hh * 32 + (lane >> 4) * 8 + j;
        int cc = t * 16 + (lane & 15);
        wp1[i] = bf16r(W1[k * 64 + cc]);
        wph[i] = bf16r(Wh[k * 64 + cc]);
        if (t < 3) wp2[i] = bf16r(cc < 40 ? W2[k * 40 + cc] : 0.f);
    } else {
        int i = (bid - 16) * 256 + threadIdx.x;
        if (i < n4) {
            float4 v = *(const float4*)(x + (size_t)i * 4);
            ushort4 o;
            o.x = bf16r(v.x); o.y = bf16r(v.y); o.z = bf16r(v.z); o.w = bf16r(v.w);
            *(ushort4*)(xb + (size_t)i * 4) = o;
        }
    }
}

// ---------------- fused layer: out = act( (Â·h) @ W + b ) ----------------
// One wave per 16-node tile. Per node: r5's proven gather loop (lane =
// edge-slot(3b) x channel-oct(3b), uint4 = 8 bf16 channels, 16 edges in
// flight, adjacency prefetched, self-loop folded as virtual edge). Result row
// parked in wave-private LDS in A-fragment order: slot o*16+m holds channels
// 8o..8o+7 of node m, so the A-frag read is ds_read_b128 at lane*16 —
// conflict-free. Then 2 MFMA per 16-col tile + bias/ReLU or log-softmax.
// No barriers (wave-local LDS only).

template <int NT, bool LSM>   // NT = # of 16-col output tiles (4 => 64ch, 3 => 40ch)
__launch_bounds__(256, 8)
__global__ void gcn_fused(const unsigned short* __restrict__ h, const int* __restrict__ row_ptr,
                          const int* __restrict__ col, const float* __restrict__ dinv,
                          const float* __restrict__ bias, const unsigned short* __restrict__ wp,
                          void* __restrict__ outv, int n, int nTiles) {
    __shared__ uint4 As[4][128];   // 4 waves x (8 ch-octs x 16 nodes) x 16B
    int tid = threadIdx.x;
    int w = tid >> 6;
    int lane = tid & 63;
    int tile = blockIdx.x * 4 + w;
    if (tile >= nTiles) return;

    int sub = lane >> 3;        // edge slot 0..7
    int ch8 = (lane & 7) * 8;   // channel base
    int nodeBase = tile * 16;

    for (int m = 0; m < 16; ++m) {
        int node = nodeBase + m;
        uint4 pk = make_uint4(0, 0, 0, 0);
        if (node < n) {                       // wave-uniform guard
            int beg = row_ptr[node];
            int deg = row_ptr[node + 1] - beg;
            float di = dinv[node];
            int total = deg + 1;              // + virtual self edge (weight di)

            float acc[8];
#pragma unroll
            for (int j = 0; j < 8; ++j) acc[j] = 0.f;

            int base = 0;
            while (base < total) {
                int vi = base + lane;
                int idx = node;
                float dw = 0.f;
                if (vi < deg) {
                    idx = col[beg + vi];
                    dw = dinv[idx];
                } else if (vi == deg) {
                    dw = di;                  // self edge
                }
                int cnt = min(total - base, 64);
                for (int c0 = 0; c0 < cnt; c0 += 16) {
                    int e0 = c0 + sub;
                    int e1 = c0 + 8 + sub;
                    int s0 = __shfl(idx, e0);
                    float d0 = __shfl(dw, e0);
                    int s1 = __shfl(idx, e1);
                    float d1 = __shfl(dw, e1);
                    uint4 u0 = make_uint4(0, 0, 0, 0);
                    uint4 u1 = make_uint4(0, 0, 0, 0);
                    if (e0 < cnt) u0 = *(const uint4*)(h + (size_t)s0 * 64 + ch8); else d0 = 0.f;
                    if (e1 < cnt) u1 = *(const uint4*)(h + (size_t)s1 * 64 + ch8); else d1 = 0.f;
                    acc[0] += d0 * bf_lo(u0.x); acc[1] += d0 * bf_hi(u0.x);
                    acc[2] += d0 * bf_lo(u0.y); acc[3] += d0 * bf_hi(u0.y);
                    acc[4] += d0 * bf_lo(u0.z); acc[5] += d0 * bf_hi(u0.z);
                    acc[6] += d0 * bf_lo(u0.w); acc[7] += d0 * bf_hi(u0.w);
                    acc[0] += d1 * bf_lo(u1.x); acc[1] += d1 * bf_hi(u1.x);
                    acc[2] += d1 * bf_lo(u1.y); acc[3] += d1 * bf_hi(u1.y);
                    acc[4] += d1 * bf_lo(u1.z); acc[5] += d1 * bf_hi(u1.z);
                    acc[6] += d1 * bf_lo(u1.w); acc[7] += d1 * bf_hi(u1.w);
                }
                base += cnt;
            }
            // reduce the 8 edge slots (lane bits 3,4,5)
#pragma unroll
            for (int off = 8; off <= 32; off <<= 1) {
#pragma unroll
                for (int j = 0; j < 8; ++j) acc[j] += __shfl_xor(acc[j], off);
            }
            pk.x = (unsigned)bf16r(di * acc[0]) | ((unsigned)bf16r(di * acc[1]) << 16);
            pk.y = (unsigned)bf16r(di * acc[2]) | ((unsigned)bf16r(di * acc[3]) << 16);
            pk.z = (unsigned)bf16r(di * acc[4]) | ((unsigned)bf16r(di * acc[5]) << 16);
            pk.w = (unsigned)bf16r(di * acc[6]) | ((unsigned)bf16r(di * acc[7]) << 16);
        }
        if (sub == 0) As[w][(lane << 4) + m] = pk;   // slot o*16+m, o = lane 0..7
    }
    // wave-local LDS write -> read; compiler inserts lgkm waits, no barrier.

    int q = lane >> 4, c = lane & 15;
    bf16x8 a0 = __builtin_bit_cast(bf16x8, As[w][lane]);        // (g=q,   m=c)
    bf16x8 a1 = __builtin_bit_cast(bf16x8, As[w][lane + 64]);   // (g=q+4, m=c)

    f32x4 acc2[NT];
#pragma unroll
    for (int t = 0; t < NT; ++t) {
        bf16x8 bf0 = *(const bf16x8*)(wp + t * 1024 + lane * 8);
        bf16x8 bf1 = *(const bf16x8*)(wp + t * 1024 + 512 + lane * 8);
        f32x4 z = {0.f, 0.f, 0.f, 0.f};
        z = __builtin_amdgcn_mfma_f32_16x16x32_bf16(a0, bf0, z, 0, 0, 0);
        z = __builtin_amdgcn_mfma_f32_16x16x32_bf16(a1, bf1, z, 0, 0, 0);
        acc2[t] = z;
    }

    if (!LSM) {
#pragma unroll
        for (int r = 0; r < 4; ++r) {
            int node = nodeBase + q * 4 + r;
            if (node < n) {
                unsigned short* orow = (unsigned short*)outv + (size_t)node * 64;
#pragma unroll
                for (int t = 0; t < NT; ++t)
                    orow[t * 16 + c] = bf16r(fmaxf(acc2[t][r] + bias[t * 16 + c], 0.f));
            }
        }
    } else {
        bool v2ok = (c < 8);   // col 32+c < 40
        float bs0 = bias[c];
        float bs1 = bias[16 + c];
        float bs2 = v2ok ? bias[32 + c] : 0.f;
#pragma unroll
        for (int r = 0; r < 4; ++r) {
            int node = nodeBase + q * 4 + r;
            float v0 = acc2[0][r] + bs0;
            float v1 = acc2[1][r] + bs1;
            float v2 = v2ok ? (acc2[2][r] + bs2) : -INFINITY;
            float mx = fmaxf(fmaxf(v0, v1), v2);
#pragma unroll
            for (int off = 1; off <= 8; off <<= 1) mx = fmaxf(mx, __shfl_xor(mx, off));
            float s = expf(v0 - mx) + expf(v1 - mx) + (v2ok ? expf(v2 - mx) : 0.f);
#pragma unroll
            for (int off = 1; off <= 8; off <<= 1) s += __shfl_xor(s, off);
            if (node < n) {
                float ls = mx + logf(s);
                float* orow = (float*)outv + (size_t)node * 40;
                orow[c] = v0 - ls;
                orow[16 + c] = v1 - ls;
                if (v2ok) orow[32 + c] = v2 - ls;
            }
        }
    }
}

// ---------------- launch ----------------

extern "C" void kernel_launch(void* const* d_in, const int* in_sizes, int n_in,
                              void* d_out, int out_size, void* d_ws, size_t ws_size,
                              hipStream_t stream) {
    const float* x  = (const float*)d_in[0];
    const int* ei   = (const int*)d_in[1];
    const float* W1 = (const float*)d_in[2];
    const float* b1 = (const float*)d_in[3];
    const float* Wh = (const float*)d_in[4];
    const float* bh = (const float*)d_in[5];
    const float* W2 = (const float*)d_in[6];
    const float* b2 = (const float*)d_in[7];
    float* out = (float*)d_out;

    const int N = in_sizes[0] / 64;
    const int E = in_sizes[1] / 2;
    const int nbuk = (N + 511) >> 9;         // 512-node buckets (needs N <= 131072)
    const int nTiles = (N + 15) / 16;
    const int Npad = nTiles * 16;

    const int* srcp = ei;
    const int* dstp = ei + E;

    size_t off = 0;
    auto alloc = [&](size_t bytes) {
        size_t o = off;
        off = (off + bytes + 255) & ~(size_t)255;
        return o;
    };
    char* ws = (char*)d_ws;
    int*      cntg    = (int*)(ws + alloc(256 * 4));
    int*      bstart  = (int*)(ws + alloc(257 * 4));
    int*      row_ptr = (int*)(ws + alloc((size_t)(N + 1) * 4));
    float*    dinv    = (float*)(ws + alloc((size_t)N * 4));
    int*      col     = (int*)(ws + alloc((size_t)E * 4));
    unsigned* ebuf    = (unsigned*)(ws + alloc((size_t)nbuk * BCAP * 4));
    unsigned short* wp1  = (unsigned short*)(ws + alloc(4096 * 2));
    unsigned short* wph  = (unsigned short*)(ws + alloc(4096 * 2));
    unsigned short* wp2  = (unsigned short*)(ws + alloc(3072 * 2));
    unsigned short* xb   = (unsigned short*)(ws + alloc((size_t)Npad * 64 * 2));
    unsigned short* gA   = (unsigned short*)(ws + alloc((size_t)Npad * 64 * 2));
    unsigned short* gB   = (unsigned short*)(ws + alloc((size_t)Npad * 64 * 2));
    (void)ws_size;

    hipMemsetAsync(cntg, 0, 256 * 4, stream);

    const int ebGrid = (E + 256 * EPT - 1) / (256 * EPT);
    scat1_kernel<<<ebGrid, 256, 0, stream>>>(srcp, dstp, cntg, ebuf, E);
    bscan_kernel<<<1, 256, 0, stream>>>(cntg, bstart);
    build_kernel<<<nbuk, 256, 0, stream>>>(ebuf, cntg, bstart, row_ptr, col, dinv, N, E);

    const int n4 = N * 64 / 4;
    cvtpack_kernel<<<16 + (n4 + 255) / 256, 256, 0, stream>>>(x, xb, n4, W1, Wh, W2, wp1, wph, wp2);

    const int fusedGrid = (nTiles + 3) / 4;

    // layer 1: relu( (Â·x) @ W1 + b1 ) -> gA (bf16)
    gcn_fused<4, false><<<fusedGrid, 256, 0, stream>>>(xb, row_ptr, col, dinv, b1, wp1, gA, N, nTiles);
    // layer 2: relu( (Â·gA) @ Wh + bh ) -> gB (bf16)
    gcn_fused<4, false><<<fusedGrid, 256, 0, stream>>>(gA, row_ptr, col, dinv, bh, wph, gB, N, nTiles);
    // layer 3: log_softmax( (Â·gB) @ W2 + b2 ) -> out (fp32)
    gcn_fused<3, true><<<fusedGrid, 256, 0, stream>>>(gB, row_ptr, col, dinv, b2, wp2, out, N, nTiles);
}

// Round 8
// 298.144 us; speedup vs baseline: 1.0490x; 1.0128x over previous
//
#include <hip/hip_runtime.h>
#include <hip/hip_bf16.h>
#include <math.h>

#define EPT 16      // edges per thread in scatter kernel
#define BCAP 16384  // bucket capacity (avg ~8.2k for uniform random, +90 sigma)

typedef _Float16 half8 __attribute__((ext_vector_type(8)));
typedef float f32x4 __attribute__((ext_vector_type(4)));

__device__ __forceinline__ unsigned short f16r(float f) {
    _Float16 h = (_Float16)f;
    return __builtin_bit_cast(unsigned short, h);
}

// ---------------- CSR build: single-pass 512-node bucket binning ----------------
// bucket b = dst >> 9; edge record = (src << 9) | (dst & 511)  [needs N <= 131072]

__global__ void scat1_kernel(const int* __restrict__ src, const int* __restrict__ dst,
                             int* __restrict__ cntg, unsigned* __restrict__ ebuf, int E) {
    __shared__ int lh[256];
    __shared__ int lbase[256];
    int tid = threadIdx.x;
    lh[tid] = 0;
    __syncthreads();
    int base = blockIdx.x * (256 * EPT);
    for (int k = 0; k < EPT; ++k) {
        int e = base + k * 256 + tid;
        if (e < E) atomicAdd(&lh[dst[e] >> 9], 1);
    }
    __syncthreads();
    if (lh[tid] > 0) lbase[tid] = atomicAdd(&cntg[tid], lh[tid]);
    lh[tid] = 0;
    __syncthreads();
    for (int k = 0; k < EPT; ++k) {
        int e = base + k * 256 + tid;
        if (e < E) {
            int s = src[e], d = dst[e];
            int b = d >> 9;
            int pos = lbase[b] + atomicAdd(&lh[b], 1);
            ebuf[(size_t)b * BCAP + pos] = ((unsigned)s << 9) | (unsigned)(d & 511);
        }
    }
}

// exclusive scan of the 256 bucket counts -> global CSR bucket offsets
__global__ void bscan_kernel(const int* __restrict__ cntg, int* __restrict__ bstart) {
    __shared__ int sh[256];
    int tid = threadIdx.x;
    int v = cntg[tid];
    sh[tid] = v;
    __syncthreads();
    int val = v;
    for (int off = 1; off < 256; off <<= 1) {
        int add = 0;
        if (tid >= off) add = sh[tid - off];
        __syncthreads();
        val += add;
        sh[tid] = val;
        __syncthreads();
    }
    bstart[tid] = val - v;
    if (tid == 255) bstart[256] = val;
}

// one block per bucket: local degrees -> scan -> row_ptr/dinv -> fine scatter
__global__ void build_kernel(const unsigned* __restrict__ ebuf, const int* __restrict__ cntg,
                             const int* __restrict__ bstart, int* __restrict__ row_ptr,
                             int* __restrict__ col, float* __restrict__ dinv, int N, int E) {
    __shared__ int deg[512];
    __shared__ int sh[256];
    int b = blockIdx.x;
    int tid = threadIdx.x;
    int nodeBase = b << 9;
    int nn = N - nodeBase;
    if (nn > 512) nn = 512;
    if (nn < 0) nn = 0;
    const unsigned* eb = ebuf + (size_t)b * BCAP;
    int cnt = cntg[b];
    int start = bstart[b];

    deg[tid] = 0;
    deg[tid + 256] = 0;
    __syncthreads();
    for (int j = tid; j < cnt; j += 256) {
        atomicAdd(&deg[eb[j] & 511u], 1);
    }
    __syncthreads();

    int i0 = tid * 2, i1 = i0 + 1;
    int v0 = deg[i0], v1 = deg[i1];
    int tot = v0 + v1;
    sh[tid] = tot;
    __syncthreads();
    int val = tot;
    for (int off = 1; off < 256; off <<= 1) {
        int add = 0;
        if (tid >= off) add = sh[tid - off];
        __syncthreads();
        val += add;
        sh[tid] = val;
        __syncthreads();
    }
    int excl = val - tot;

    if (i0 < nn) { row_ptr[nodeBase + i0] = start + excl;      dinv[nodeBase + i0] = rsqrtf((float)v0 + 1.0f); }
    if (i1 < nn) { row_ptr[nodeBase + i1] = start + excl + v0; dinv[nodeBase + i1] = rsqrtf((float)v1 + 1.0f); }
    if (b == 0 && tid == 0) row_ptr[N] = E;
    // repurpose deg[] as absolute write cursors
    deg[i0] = start + excl;
    deg[i1] = start + excl + v0;
    __syncthreads();

    for (int j = tid; j < cnt; j += 256) {
        unsigned rec = eb[j];
        int pos = atomicAdd(&deg[rec & 511u], 1);
        col[pos] = (int)(rec >> 9);
    }
}

// ---------------- fused convert + weight pack (fp16) ----------------
// blocks [0,16): pack W1/Wh/W2 into MFMA B-fragment order (fp16):
//   wp[t*1024 + h*512 + lane*8 + j] = W[h*32 + (lane>>4)*8 + j][t*16 + (lane&15)]
// blocks [16, ...): fp32 -> fp16 convert of x.

__global__ void cvtpack_kernel(const float* __restrict__ x, unsigned short* __restrict__ xb,
                               int n4, const float* __restrict__ W1, const float* __restrict__ Wh,
                               const float* __restrict__ W2, unsigned short* __restrict__ wp1,
                               unsigned short* __restrict__ wph, unsigned short* __restrict__ wp2) {
    int bid = blockIdx.x;
    if (bid < 16) {
        int i = bid * 256 + threadIdx.x;   // i in [0,4096)
        int j = i & 7;
        int lane = (i >> 3) & 63;
        int hh = (i >> 9) & 1;
        int t = i >> 10;
        int k = hh * 32 + (lane >> 4) * 8 + j;
        int cc = t * 16 + (lane & 15);
        wp1[i] = f16r(W1[k * 64 + cc]);
        wph[i] = f16r(Wh[k * 64 + cc]);
        if (t < 3) wp2[i] = f16r(cc < 40 ? W2[k * 40 + cc] : 0.f);
    } else {
        int i = (bid - 16) * 256 + threadIdx.x;
        if (i < n4) {
            float4 v = *(const float4*)(x + (size_t)i * 4);
            ushort4 o;
            o.x = f16r(v.x); o.y = f16r(v.y); o.z = f16r(v.z); o.w = f16r(v.w);
            *(ushort4*)(xb + (size_t)i * 4) = o;
        }
    }
}

// ---------------- fused layer: out = act( (Â·h) @ W + b ), fp16 storage -----
// 128-thread blocks, 2 waves, one 16-node tile per wave (grid = nTiles/2 for
// fine-grained CU packing). Per node: gather with lane = edge-slot(3b) x
// channel-oct(3b), uint4 = 8 fp16 channels, 16 edges in flight, adjacency
// prefetched, self-loop folded as virtual edge. fp16->fp32 accumulate maps to
// v_fma_mix_f32 (no unpack ALU). Row parked in wave-private LDS in A-fragment
// order (slot o*16+m), then 2 MFMA (f16) per 16-col tile + epilogue. No
// barriers (wave-local LDS only).

template <int NT, bool LSM>   // NT = # of 16-col output tiles (4 => 64ch, 3 => 40ch)
__launch_bounds__(128, 8)
__global__ void gcn_fused(const unsigned short* __restrict__ h, const int* __restrict__ row_ptr,
                          const int* __restrict__ col, const float* __restrict__ dinv,
                          const float* __restrict__ bias, const unsigned short* __restrict__ wp,
                          void* __restrict__ outv, int n, int nTiles) {
    __shared__ uint4 As[2][128];   // 2 waves x (8 ch-octs x 16 nodes) x 16B
    int tid = threadIdx.x;
    int w = tid >> 6;
    int lane = tid & 63;
    int tile = blockIdx.x * 2 + w;
    if (tile >= nTiles) return;

    int sub = lane >> 3;        // edge slot 0..7
    int ch8 = (lane & 7) * 8;   // channel base
    int nodeBase = tile * 16;

    for (int m = 0; m < 16; ++m) {
        int node = nodeBase + m;
        uint4 pk = make_uint4(0, 0, 0, 0);
        if (node < n) {                       // wave-uniform guard
            int beg = row_ptr[node];
            int deg = row_ptr[node + 1] - beg;
            float di = dinv[node];
            int total = deg + 1;              // + virtual self edge (weight di)

            float acc[8];
#pragma unroll
            for (int j = 0; j < 8; ++j) acc[j] = 0.f;

            int base = 0;
            while (base < total) {
                int vi = base + lane;
                int idx = node;
                float dw = 0.f;
                if (vi < deg) {
                    idx = col[beg + vi];
                    dw = dinv[idx];
                } else if (vi == deg) {
                    dw = di;                  // self edge
                }
                int cnt = min(total - base, 64);
                for (int c0 = 0; c0 < cnt; c0 += 16) {
                    int e0 = c0 + sub;
                    int e1 = c0 + 8 + sub;
                    int s0 = __shfl(idx, e0);
                    float d0 = __shfl(dw, e0);
                    int s1 = __shfl(idx, e1);
                    float d1 = __shfl(dw, e1);
                    uint4 u0 = make_uint4(0, 0, 0, 0);
                    uint4 u1 = make_uint4(0, 0, 0, 0);
                    if (e0 < cnt) u0 = *(const uint4*)(h + (size_t)s0 * 64 + ch8); else d0 = 0.f;
                    if (e1 < cnt) u1 = *(const uint4*)(h + (size_t)s1 * 64 + ch8); else d1 = 0.f;
                    half8 v0 = __builtin_bit_cast(half8, u0);
                    half8 v1 = __builtin_bit_cast(half8, u1);
#pragma unroll
                    for (int j = 0; j < 8; ++j) {
                        acc[j] += (float)v0[j] * d0;   // -> v_fma_mix_f32
                        acc[j] += (float)v1[j] * d1;
                    }
                }
                base += cnt;
            }
            // reduce the 8 edge slots (lane bits 3,4,5)
#pragma unroll
            for (int off = 8; off <= 32; off <<= 1) {
#pragma unroll
                for (int j = 0; j < 8; ++j) acc[j] += __shfl_xor(acc[j], off);
            }
            pk.x = (unsigned)f16r(di * acc[0]) | ((unsigned)f16r(di * acc[1]) << 16);
            pk.y = (unsigned)f16r(di * acc[2]) | ((unsigned)f16r(di * acc[3]) << 16);
            pk.z = (unsigned)f16r(di * acc[4]) | ((unsigned)f16r(di * acc[5]) << 16);
            pk.w = (unsigned)f16r(di * acc[6]) | ((unsigned)f16r(di * acc[7]) << 16);
        }
        if (sub == 0) As[w][(lane << 4) + m] = pk;   // slot o*16+m, o = lane 0..7
    }
    // wave-local LDS write -> read; compiler inserts lgkm waits, no barrier.

    int q = lane >> 4, c = lane & 15;
    half8 a0 = __builtin_bit_cast(half8, As[w][lane]);        // (g=q,   m=c)
    half8 a1 = __builtin_bit_cast(half8, As[w][lane + 64]);   // (g=q+4, m=c)

    f32x4 acc2[NT];
#pragma unroll
    for (int t = 0; t < NT; ++t) {
        half8 bf0 = *(const half8*)(wp + t * 1024 + lane * 8);
        half8 bf1 = *(const half8*)(wp + t * 1024 + 512 + lane * 8);
        f32x4 z = {0.f, 0.f, 0.f, 0.f};
        z = __builtin_amdgcn_mfma_f32_16x16x32_f16(a0, bf0, z, 0, 0, 0);
        z = __builtin_amdgcn_mfma_f32_16x16x32_f16(a1, bf1, z, 0, 0, 0);
        acc2[t] = z;
    }

    if (!LSM) {
#pragma unroll
        for (int r = 0; r < 4; ++r) {
            int node = nodeBase + q * 4 + r;
            if (node < n) {
                unsigned short* orow = (unsigned short*)outv + (size_t)node * 64;
#pragma unroll
                for (int t = 0; t < NT; ++t)
                    orow[t * 16 + c] = f16r(fmaxf(acc2[t][r] + bias[t * 16 + c], 0.f));
            }
        }
    } else {
        bool v2ok = (c < 8);   // col 32+c < 40
        float bs0 = bias[c];
        float bs1 = bias[16 + c];
        float bs2 = v2ok ? bias[32 + c] : 0.f;
#pragma unroll
        for (int r = 0; r < 4; ++r) {
            int node = nodeBase + q * 4 + r;
            float v0 = acc2[0][r] + bs0;
            float v1 = acc2[1][r] + bs1;
            float v2 = v2ok ? (acc2[2][r] + bs2) : -INFINITY;
            float mx = fmaxf(fmaxf(v0, v1), v2);
#pragma unroll
            for (int off = 1; off <= 8; off <<= 1) mx = fmaxf(mx, __shfl_xor(mx, off));
            float s = expf(v0 - mx) + expf(v1 - mx) + (v2ok ? expf(v2 - mx) : 0.f);
#pragma unroll
            for (int off = 1; off <= 8; off <<= 1) s += __shfl_xor(s, off);
            if (node < n) {
                float ls = mx + logf(s);
                float* orow = (float*)outv + (size_t)node * 40;
                orow[c] = v0 - ls;
                orow[16 + c] = v1 - ls;
                if (v2ok) orow[32 + c] = v2 - ls;
            }
        }
    }
}

// ---------------- launch ----------------

extern "C" void kernel_launch(void* const* d_in, const int* in_sizes, int n_in,
                              void* d_out, int out_size, void* d_ws, size_t ws_size,
                              hipStream_t stream) {
    const float* x  = (const float*)d_in[0];
    const int* ei   = (const int*)d_in[1];
    const float* W1 = (const float*)d_in[2];
    const float* b1 = (const float*)d_in[3];
    const float* Wh = (const float*)d_in[4];
    const float* bh = (const float*)d_in[5];
    const float* W2 = (const float*)d_in[6];
    const float* b2 = (const float*)d_in[7];
    float* out = (float*)d_out;

    const int N = in_sizes[0] / 64;
    const int E = in_sizes[1] / 2;
    const int nbuk = (N + 511) >> 9;         // 512-node buckets (needs N <= 131072)
    const int nTiles = (N + 15) / 16;
    const int Npad = nTiles * 16;

    const int* srcp = ei;
    const int* dstp = ei + E;

    size_t off = 0;
    auto alloc = [&](size_t bytes) {
        size_t o = off;
        off = (off + bytes + 255) & ~(size_t)255;
        return o;
    };
    char* ws = (char*)d_ws;
    int*      cntg    = (int*)(ws + alloc(256 * 4));
    int*      bstart  = (int*)(ws + alloc(257 * 4));
    int*      row_ptr = (int*)(ws + alloc((size_t)(N + 1) * 4));
    float*    dinv    = (float*)(ws + alloc((size_t)N * 4));
    int*      col     = (int*)(ws + alloc((size_t)E * 4));
    unsigned* ebuf    = (unsigned*)(ws + alloc((size_t)nbuk * BCAP * 4));
    unsigned short* wp1  = (unsigned short*)(ws + alloc(4096 * 2));
    unsigned short* wph  = (unsigned short*)(ws + alloc(4096 * 2));
    unsigned short* wp2  = (unsigned short*)(ws + alloc(3072 * 2));
    unsigned short* xb   = (unsigned short*)(ws + alloc((size_t)Npad * 64 * 2));
    unsigned short* gA   = (unsigned short*)(ws + alloc((size_t)Npad * 64 * 2));
    unsigned short* gB   = (unsigned short*)(ws + alloc((size_t)Npad * 64 * 2));
    (void)ws_size;

    hipMemsetAsync(cntg, 0, 256 * 4, stream);

    const int ebGrid = (E + 256 * EPT - 1) / (256 * EPT);
    scat1_kernel<<<ebGrid, 256, 0, stream>>>(srcp, dstp, cntg, ebuf, E);
    bscan_kernel<<<1, 256, 0, stream>>>(cntg, bstart);
    build_kernel<<<nbuk, 256, 0, stream>>>(ebuf, cntg, bstart, row_ptr, col, dinv, N, E);

    const int n4 = N * 64 / 4;
    cvtpack_kernel<<<16 + (n4 + 255) / 256, 256, 0, stream>>>(x, xb, n4, W1, Wh, W2, wp1, wph, wp2);

    const int fusedGrid = (nTiles + 1) / 2;

    // layer 1: relu( (Â·x) @ W1 + b1 ) -> gA (fp16)
    gcn_fused<4, false><<<fusedGrid, 128, 0, stream>>>(xb, row_ptr, col, dinv, b1, wp1, gA, N, nTiles);
    // layer 2: relu( (Â·gA) @ Wh + bh ) -> gB (fp16)
    gcn_fused<4, false><<<fusedGrid, 128, 0, stream>>>(gA, row_ptr, col, dinv, bh, wph, gB, N, nTiles);
    // layer 3: log_softmax( (Â·gB) @ W2 + b2 ) -> out (fp32)
    gcn_fused<3, true><<<fusedGrid, 128, 0, stream>>>(gB, row_ptr, col, dinv, b2, wp2, out, N, nTiles);
}

// Round 9
// 291.696 us; speedup vs baseline: 1.0722x; 1.0221x over previous
//
#include <hip/hip_runtime.h>
#include <hip/hip_bf16.h>
#include <math.h>

#define EPT 16      // edges per thread in scatter kernel
#define BCAP 16384  // bucket capacity (avg ~8.2k for uniform random, +90 sigma)

typedef _Float16 half8 __attribute__((ext_vector_type(8)));
typedef float f32x4 __attribute__((ext_vector_type(4)));

__device__ __forceinline__ unsigned short f16r(float f) {
    _Float16 h = (_Float16)f;
    return __builtin_bit_cast(unsigned short, h);
}

// ---------------- CSR build: single-pass 512-node bucket binning ----------------
// bucket b = dst >> 9; edge record = (src << 9) | (dst & 511)  [needs N <= 131072]

__global__ void scat1_kernel(const int* __restrict__ src, const int* __restrict__ dst,
                             int* __restrict__ cntg, unsigned* __restrict__ ebuf, int E) {
    __shared__ int lh[256];
    __shared__ int lbase[256];
    int tid = threadIdx.x;
    lh[tid] = 0;
    __syncthreads();
    int base = blockIdx.x * (256 * EPT);
    for (int k = 0; k < EPT; ++k) {
        int e = base + k * 256 + tid;
        if (e < E) atomicAdd(&lh[dst[e] >> 9], 1);
    }
    __syncthreads();
    if (lh[tid] > 0) lbase[tid] = atomicAdd(&cntg[tid], lh[tid]);
    lh[tid] = 0;
    __syncthreads();
    for (int k = 0; k < EPT; ++k) {
        int e = base + k * 256 + tid;
        if (e < E) {
            int s = src[e], d = dst[e];
            int b = d >> 9;
            int pos = lbase[b] + atomicAdd(&lh[b], 1);
            ebuf[(size_t)b * BCAP + pos] = ((unsigned)s << 9) | (unsigned)(d & 511);
        }
    }
}

// exclusive scan of the 256 bucket counts -> global CSR bucket offsets
__global__ void bscan_kernel(const int* __restrict__ cntg, int* __restrict__ bstart) {
    __shared__ int sh[256];
    int tid = threadIdx.x;
    int v = cntg[tid];
    sh[tid] = v;
    __syncthreads();
    int val = v;
    for (int off = 1; off < 256; off <<= 1) {
        int add = 0;
        if (tid >= off) add = sh[tid - off];
        __syncthreads();
        val += add;
        sh[tid] = val;
        __syncthreads();
    }
    bstart[tid] = val - v;
    if (tid == 255) bstart[256] = val;
}

// one block per bucket: local degrees -> scan -> row_ptr/dinv -> fine scatter
__global__ void build_kernel(const unsigned* __restrict__ ebuf, const int* __restrict__ cntg,
                             const int* __restrict__ bstart, int* __restrict__ row_ptr,
                             int* __restrict__ col, float* __restrict__ dinv, int N, int E) {
    __shared__ int deg[512];
    __shared__ int sh[256];
    int b = blockIdx.x;
    int tid = threadIdx.x;
    int nodeBase = b << 9;
    int nn = N - nodeBase;
    if (nn > 512) nn = 512;
    if (nn < 0) nn = 0;
    const unsigned* eb = ebuf + (size_t)b * BCAP;
    int cnt = cntg[b];
    int start = bstart[b];

    deg[tid] = 0;
    deg[tid + 256] = 0;
    __syncthreads();
    for (int j = tid; j < cnt; j += 256) {
        atomicAdd(&deg[eb[j] & 511u], 1);
    }
    __syncthreads();

    int i0 = tid * 2, i1 = i0 + 1;
    int v0 = deg[i0], v1 = deg[i1];
    int tot = v0 + v1;
    sh[tid] = tot;
    __syncthreads();
    int val = tot;
    for (int off = 1; off < 256; off <<= 1) {
        int add = 0;
        if (tid >= off) add = sh[tid - off];
        __syncthreads();
        val += add;
        sh[tid] = val;
        __syncthreads();
    }
    int excl = val - tot;

    if (i0 < nn) { row_ptr[nodeBase + i0] = start + excl;      dinv[nodeBase + i0] = rsqrtf((float)v0 + 1.0f); }
    if (i1 < nn) { row_ptr[nodeBase + i1] = start + excl + v0; dinv[nodeBase + i1] = rsqrtf((float)v1 + 1.0f); }
    if (b == 0 && tid == 0) row_ptr[N] = E;
    // repurpose deg[] as absolute write cursors
    deg[i0] = start + excl;
    deg[i1] = start + excl + v0;
    __syncthreads();

    for (int j = tid; j < cnt; j += 256) {
        unsigned rec = eb[j];
        int pos = atomicAdd(&deg[rec & 511u], 1);
        col[pos] = (int)(rec >> 9);
    }
}

// ---------------- fused convert + weight pack (fp16) ----------------
// blocks [0,16): pack W1/Wh/W2 into MFMA B-fragment order (fp16):
//   wp[t*1024 + h*512 + lane*8 + j] = W[h*32 + (lane>>4)*8 + j][t*16 + (lane&15)]
// blocks [16, ...): fp32 -> fp16 convert of x.

__global__ void cvtpack_kernel(const float* __restrict__ x, unsigned short* __restrict__ xb,
                               int n4, const float* __restrict__ W1, const float* __restrict__ Wh,
                               const float* __restrict__ W2, unsigned short* __restrict__ wp1,
                               unsigned short* __restrict__ wph, unsigned short* __restrict__ wp2) {
    int bid = blockIdx.x;
    if (bid < 16) {
        int i = bid * 256 + threadIdx.x;   // i in [0,4096)
        int j = i & 7;
        int lane = (i >> 3) & 63;
        int hh = (i >> 9) & 1;
        int t = i >> 10;
        int k = hh * 32 + (lane >> 4) * 8 + j;
        int cc = t * 16 + (lane & 15);
        wp1[i] = f16r(W1[k * 64 + cc]);
        wph[i] = f16r(Wh[k * 64 + cc]);
        if (t < 3) wp2[i] = f16r(cc < 40 ? W2[k * 40 + cc] : 0.f);
    } else {
        int i = (bid - 16) * 256 + threadIdx.x;
        if (i < n4) {
            float4 v = *(const float4*)(x + (size_t)i * 4);
            ushort4 o;
            o.x = f16r(v.x); o.y = f16r(v.y); o.z = f16r(v.z); o.w = f16r(v.w);
            *(ushort4*)(xb + (size_t)i * 4) = o;
        }
    }
}

// ---------------- aggregation: agg[node] = di*( sum dinv[s]*h[s] + di*h[node] ) ----
// r5's proven TLP structure: one wave per node (100k waves). lane =
// edge-slot(3b) x channel-oct(3b); uint4 = 8 fp16 channels, 8 edges per
// wave-instruction, 16 edges in flight. Adjacency prefetched to registers,
// self-loop folded as virtual edge. fp16 accumulate -> v_fma_mix_f32 (no
// unpack ALU, ~half the inner-loop VALU of the bf16 version).

__launch_bounds__(256, 8)
__global__ void agg_kernel(const unsigned short* __restrict__ h, const int* __restrict__ row_ptr,
                           const int* __restrict__ col, const float* __restrict__ dinv,
                           unsigned short* __restrict__ aggout, int n) {
    int tid = threadIdx.x;
    int lane = tid & 63;
    int node = blockIdx.x * 4 + (tid >> 6);
    if (node >= n) return;

    int sub = lane >> 3;        // edge slot 0..7
    int ch8 = (lane & 7) * 8;   // channel base

    int beg = row_ptr[node];
    int deg = row_ptr[node + 1] - beg;
    float di = dinv[node];
    int total = deg + 1;        // + virtual self edge (weight di)

    float acc[8];
#pragma unroll
    for (int j = 0; j < 8; ++j) acc[j] = 0.f;

    int base = 0;
    while (base < total) {
        int vi = base + lane;
        int idx = node;
        float dw = 0.f;
        if (vi < deg) {
            idx = col[beg + vi];
            dw = dinv[idx];
        } else if (vi == deg) {
            dw = di;            // self edge
        }
        int cnt = min(total - base, 64);
        for (int c0 = 0; c0 < cnt; c0 += 16) {
            int e0 = c0 + sub;
            int e1 = c0 + 8 + sub;
            int s0 = __shfl(idx, e0);
            float d0 = __shfl(dw, e0);
            int s1 = __shfl(idx, e1);
            float d1 = __shfl(dw, e1);
            uint4 u0 = make_uint4(0, 0, 0, 0);
            uint4 u1 = make_uint4(0, 0, 0, 0);
            if (e0 < cnt) u0 = *(const uint4*)(h + (size_t)s0 * 64 + ch8); else d0 = 0.f;
            if (e1 < cnt) u1 = *(const uint4*)(h + (size_t)s1 * 64 + ch8); else d1 = 0.f;
            half8 v0 = __builtin_bit_cast(half8, u0);
            half8 v1 = __builtin_bit_cast(half8, u1);
#pragma unroll
            for (int j = 0; j < 8; ++j) {
                acc[j] += (float)v0[j] * d0;   // -> v_fma_mix_f32
                acc[j] += (float)v1[j] * d1;
            }
        }
        base += cnt;
    }
    // reduce the 8 edge slots (lane bits 3,4,5)
#pragma unroll
    for (int off = 8; off <= 32; off <<= 1) {
#pragma unroll
        for (int j = 0; j < 8; ++j) acc[j] += __shfl_xor(acc[j], off);
    }

    if (sub == 0) {
        unsigned p0 = (unsigned)f16r(di * acc[0]) | ((unsigned)f16r(di * acc[1]) << 16);
        unsigned p1 = (unsigned)f16r(di * acc[2]) | ((unsigned)f16r(di * acc[3]) << 16);
        unsigned p2 = (unsigned)f16r(di * acc[4]) | ((unsigned)f16r(di * acc[5]) << 16);
        unsigned p3 = (unsigned)f16r(di * acc[6]) | ((unsigned)f16r(di * acc[7]) << 16);
        *(uint4*)(aggout + (size_t)node * 64 + ch8) = make_uint4(p0, p1, p2, p3);
    }
}

// ---------------- MFMA epilogue GEMMs (f16) ----------------
// One wave per 16-node tile. A-frag: A[m=lane&15][k=quad*8+j] -> contiguous
// uint4 from agg buffer. B-frag from pre-packed wp. C/D: col=lane&15,
// row=quad*4+reg. (Rows >= n in the padded A buffer only affect output rows
// >= n, which are never stored.)

__global__ void gemm_relu_kernel(const unsigned short* __restrict__ A,
                                 const unsigned short* __restrict__ wp,
                                 const float* __restrict__ bias,
                                 unsigned short* __restrict__ out, int nTiles, int n) {
    int wv = blockIdx.x * 4 + (threadIdx.x >> 6);
    int lane = threadIdx.x & 63;
    if (wv >= nTiles) return;
    int q = lane >> 4, c = lane & 15;

    half8 bfrag[4][2];
#pragma unroll
    for (int t = 0; t < 4; ++t)
#pragma unroll
        for (int hh = 0; hh < 2; ++hh)
            bfrag[t][hh] = *(const half8*)(wp + t * 1024 + hh * 512 + lane * 8);
    float bs[4];
#pragma unroll
    for (int t = 0; t < 4; ++t) bs[t] = bias[t * 16 + c];

    int nodeBase = wv * 16;
    const unsigned short* arow = A + (size_t)(nodeBase + c) * 64 + q * 8;
    half8 a0 = *(const half8*)(arow);
    half8 a1 = *(const half8*)(arow + 32);

    f32x4 acc[4];
#pragma unroll
    for (int t = 0; t < 4; ++t) {
        f32x4 z = {0.f, 0.f, 0.f, 0.f};
        z = __builtin_amdgcn_mfma_f32_16x16x32_f16(a0, bfrag[t][0], z, 0, 0, 0);
        z = __builtin_amdgcn_mfma_f32_16x16x32_f16(a1, bfrag[t][1], z, 0, 0, 0);
        acc[t] = z;
    }

#pragma unroll
    for (int r = 0; r < 4; ++r) {
        int node = nodeBase + q * 4 + r;
        if (node < n) {
            unsigned short* orow = out + (size_t)node * 64;
#pragma unroll
            for (int t = 0; t < 4; ++t)
                orow[t * 16 + c] = f16r(fmaxf(acc[t][r] + bs[t], 0.f));
        }
    }
}

__global__ void gemm_lsm_kernel(const unsigned short* __restrict__ A,
                                const unsigned short* __restrict__ wp,
                                const float* __restrict__ bias,
                                float* __restrict__ out, int nTiles, int n) {
    int wv = blockIdx.x * 4 + (threadIdx.x >> 6);
    int lane = threadIdx.x & 63;
    if (wv >= nTiles) return;
    int q = lane >> 4, c = lane & 15;
    bool v2ok = (c < 8);   // col 32+c < 40

    half8 bfrag[3][2];
#pragma unroll
    for (int t = 0; t < 3; ++t)
#pragma unroll
        for (int hh = 0; hh < 2; ++hh)
            bfrag[t][hh] = *(const half8*)(wp + t * 1024 + hh * 512 + lane * 8);
    float bs[3];
    bs[0] = bias[c];
    bs[1] = bias[16 + c];
    bs[2] = v2ok ? bias[32 + c] : 0.f;

    int nodeBase = wv * 16;
    const unsigned short* arow = A + (size_t)(nodeBase + c) * 64 + q * 8;
    half8 a0 = *(const half8*)(arow);
    half8 a1 = *(const half8*)(arow + 32);

    f32x4 acc[3];
#pragma unroll
    for (int t = 0; t < 3; ++t) {
        f32x4 z = {0.f, 0.f, 0.f, 0.f};
        z = __builtin_amdgcn_mfma_f32_16x16x32_f16(a0, bfrag[t][0], z, 0, 0, 0);
        z = __builtin_amdgcn_mfma_f32_16x16x32_f16(a1, bfrag[t][1], z, 0, 0, 0);
        acc[t] = z;
    }

#pragma unroll
    for (int r = 0; r < 4; ++r) {
        int node = nodeBase + q * 4 + r;
        if (node < n) {
            float v0 = acc[0][r] + bs[0];
            float v1 = acc[1][r] + bs[1];
            float v2 = v2ok ? (acc[2][r] + bs[2]) : -INFINITY;
            float m = fmaxf(fmaxf(v0, v1), v2);
#pragma unroll
            for (int off = 1; off <= 8; off <<= 1) m = fmaxf(m, __shfl_xor(m, off));
            float s = expf(v0 - m) + expf(v1 - m) + (v2ok ? expf(v2 - m) : 0.f);
#pragma unroll
            for (int off = 1; off <= 8; off <<= 1) s += __shfl_xor(s, off);
            float ls = m + logf(s);
            float* orow = out + (size_t)node * 40;
            orow[c] = v0 - ls;
            orow[16 + c] = v1 - ls;
            if (v2ok) orow[32 + c] = v2 - ls;
        }
    }
}

// ---------------- launch ----------------

extern "C" void kernel_launch(void* const* d_in, const int* in_sizes, int n_in,
                              void* d_out, int out_size, void* d_ws, size_t ws_size,
                              hipStream_t stream) {
    const float* x  = (const float*)d_in[0];
    const int* ei   = (const int*)d_in[1];
    const float* W1 = (const float*)d_in[2];
    const float* b1 = (const float*)d_in[3];
    const float* Wh = (const float*)d_in[4];
    const float* bh = (const float*)d_in[5];
    const float* W2 = (const float*)d_in[6];
    const float* b2 = (const float*)d_in[7];
    float* out = (float*)d_out;

    const int N = in_sizes[0] / 64;
    const int E = in_sizes[1] / 2;
    const int nbuk = (N + 511) >> 9;         // 512-node buckets (needs N <= 131072)
    const int nTiles = (N + 15) / 16;
    const int Npad = nTiles * 16;

    const int* srcp = ei;
    const int* dstp = ei + E;

    size_t off = 0;
    auto alloc = [&](size_t bytes) {
        size_t o = off;
        off = (off + bytes + 255) & ~(size_t)255;
        return o;
    };
    char* ws = (char*)d_ws;
    int*      cntg    = (int*)(ws + alloc(256 * 4));
    int*      bstart  = (int*)(ws + alloc(257 * 4));
    int*      row_ptr = (int*)(ws + alloc((size_t)(N + 1) * 4));
    float*    dinv    = (float*)(ws + alloc((size_t)N * 4));
    int*      col     = (int*)(ws + alloc((size_t)E * 4));
    unsigned* ebuf    = (unsigned*)(ws + alloc((size_t)nbuk * BCAP * 4));
    unsigned short* wp1  = (unsigned short*)(ws + alloc(4096 * 2));
    unsigned short* wph  = (unsigned short*)(ws + alloc(4096 * 2));
    unsigned short* wp2  = (unsigned short*)(ws + alloc(3072 * 2));
    unsigned short* xb   = (unsigned short*)(ws + alloc((size_t)Npad * 64 * 2));
    unsigned short* aggA = (unsigned short*)(ws + alloc((size_t)Npad * 64 * 2));
    unsigned short* gA   = (unsigned short*)(ws + alloc((size_t)Npad * 64 * 2));
    (void)ws_size;

    hipMemsetAsync(cntg, 0, 256 * 4, stream);

    const int ebGrid = (E + 256 * EPT - 1) / (256 * EPT);
    scat1_kernel<<<ebGrid, 256, 0, stream>>>(srcp, dstp, cntg, ebuf, E);
    bscan_kernel<<<1, 256, 0, stream>>>(cntg, bstart);
    build_kernel<<<nbuk, 256, 0, stream>>>(ebuf, cntg, bstart, row_ptr, col, dinv, N, E);

    const int n4 = N * 64 / 4;
    cvtpack_kernel<<<16 + (n4 + 255) / 256, 256, 0, stream>>>(x, xb, n4, W1, Wh, W2, wp1, wph, wp2);

    const int aggGrid = (N + 3) / 4;
    const int gemmGrid = (nTiles + 3) / 4;

    // layer 1
    agg_kernel<<<aggGrid, 256, 0, stream>>>(xb, row_ptr, col, dinv, aggA, N);
    gemm_relu_kernel<<<gemmGrid, 256, 0, stream>>>(aggA, wp1, b1, gA, nTiles, N);
    // layer 2
    agg_kernel<<<aggGrid, 256, 0, stream>>>(gA, row_ptr, col, dinv, aggA, N);
    gemm_relu_kernel<<<gemmGrid, 256, 0, stream>>>(aggA, wph, bh, gA, nTiles, N);
    // layer 3
    agg_kernel<<<aggGrid, 256, 0, stream>>>(gA, row_ptr, col, dinv, aggA, N);
    gemm_lsm_kernel<<<gemmGrid, 256, 0, stream>>>(aggA, wp2, b2, out, nTiles, N);
}

// Round 10
// 276.461 us; speedup vs baseline: 1.1313x; 1.0551x over previous
//
#include <hip/hip_runtime.h>
#include <hip/hip_bf16.h>
#include <math.h>

#define EPT 16      // edges per thread in scatter kernel
#define BCAP 16384  // bucket capacity (avg ~8.2k for uniform random, +90 sigma)

typedef _Float16 half8 __attribute__((ext_vector_type(8)));
typedef _Float16 half2v __attribute__((ext_vector_type(2)));
typedef float f32x4 __attribute__((ext_vector_type(4)));

__device__ __forceinline__ unsigned short f16r(float f) {
    _Float16 h = (_Float16)f;
    return __builtin_bit_cast(unsigned short, h);
}

// ---------------- CSR build: single-pass 512-node bucket binning ----------------
// bucket b = dst >> 9; edge record = (src << 9) | (dst & 511)  [needs N <= 131072]

__global__ void scat1_kernel(const int* __restrict__ src, const int* __restrict__ dst,
                             int* __restrict__ cntg, unsigned* __restrict__ ebuf, int E) {
    __shared__ int lh[256];
    __shared__ int lbase[256];
    int tid = threadIdx.x;
    lh[tid] = 0;
    __syncthreads();
    int base = blockIdx.x * (256 * EPT);
    for (int k = 0; k < EPT; ++k) {
        int e = base + k * 256 + tid;
        if (e < E) atomicAdd(&lh[dst[e] >> 9], 1);
    }
    __syncthreads();
    if (lh[tid] > 0) lbase[tid] = atomicAdd(&cntg[tid], lh[tid]);
    lh[tid] = 0;
    __syncthreads();
    for (int k = 0; k < EPT; ++k) {
        int e = base + k * 256 + tid;
        if (e < E) {
            int s = src[e], d = dst[e];
            int b = d >> 9;
            int pos = lbase[b] + atomicAdd(&lh[b], 1);
            ebuf[(size_t)b * BCAP + pos] = ((unsigned)s << 9) | (unsigned)(d & 511);
        }
    }
}

// one block per bucket: inline scan of bucket counts -> local degrees -> scan
// -> row_ptr/dinv -> fine scatter  (bscan merged: each block scans redundantly)
__global__ void build_kernel(const unsigned* __restrict__ ebuf, const int* __restrict__ cntg,
                             int* __restrict__ row_ptr, int* __restrict__ col,
                             float* __restrict__ dinv, int N, int E) {
    __shared__ int deg[512];
    __shared__ int sh[256];
    int b = blockIdx.x;
    int tid = threadIdx.x;

    // block-local exclusive scan of the 256 bucket counts to get this bucket's start
    int v = cntg[tid];
    sh[tid] = v;
    __syncthreads();
    int val = v;
    for (int off = 1; off < 256; off <<= 1) {
        int add = 0;
        if (tid >= off) add = sh[tid - off];
        __syncthreads();
        val += add;
        sh[tid] = val;
        __syncthreads();
    }
    int start = (b > 0) ? sh[b - 1] : 0;   // exclusive prefix for bucket b
    int cnt = cntg[b];
    __syncthreads();

    int nodeBase = b << 9;
    int nn = N - nodeBase;
    if (nn > 512) nn = 512;
    if (nn < 0) nn = 0;
    const unsigned* eb = ebuf + (size_t)b * BCAP;

    deg[tid] = 0;
    deg[tid + 256] = 0;
    __syncthreads();
    for (int j = tid; j < cnt; j += 256) {
        atomicAdd(&deg[eb[j] & 511u], 1);
    }
    __syncthreads();

    int i0 = tid * 2, i1 = i0 + 1;
    int v0 = deg[i0], v1 = deg[i1];
    int tot = v0 + v1;
    sh[tid] = tot;
    __syncthreads();
    int val2 = tot;
    for (int off = 1; off < 256; off <<= 1) {
        int add = 0;
        if (tid >= off) add = sh[tid - off];
        __syncthreads();
        val2 += add;
        sh[tid] = val2;
        __syncthreads();
    }
    int excl = val2 - tot;

    if (i0 < nn) { row_ptr[nodeBase + i0] = start + excl;      dinv[nodeBase + i0] = rsqrtf((float)v0 + 1.0f); }
    if (i1 < nn) { row_ptr[nodeBase + i1] = start + excl + v0; dinv[nodeBase + i1] = rsqrtf((float)v1 + 1.0f); }
    if (b == 0 && tid == 0) row_ptr[N] = E;
    // repurpose deg[] as absolute write cursors
    deg[i0] = start + excl;
    deg[i1] = start + excl + v0;
    __syncthreads();

    for (int j = tid; j < cnt; j += 256) {
        unsigned rec = eb[j];
        int pos = atomicAdd(&deg[rec & 511u], 1);
        col[pos] = (int)(rec >> 9);
    }
}

// ---------------- fused convert + weight pack (fp16) ----------------
// blocks [0,16): pack W1/Wh/W2 into MFMA B-fragment order (fp16):
//   wp[t*1024 + h*512 + lane*8 + j] = W[h*32 + (lane>>4)*8 + j][t*16 + (lane&15)]
// blocks [16, ...): fp32 -> fp16 convert of x.

__global__ void cvtpack_kernel(const float* __restrict__ x, unsigned short* __restrict__ xb,
                               int n4, const float* __restrict__ W1, const float* __restrict__ Wh,
                               const float* __restrict__ W2, unsigned short* __restrict__ wp1,
                               unsigned short* __restrict__ wph, unsigned short* __restrict__ wp2) {
    int bid = blockIdx.x;
    if (bid < 16) {
        int i = bid * 256 + threadIdx.x;   // i in [0,4096)
        int j = i & 7;
        int lane = (i >> 3) & 63;
        int hh = (i >> 9) & 1;
        int t = i >> 10;
        int k = hh * 32 + (lane >> 4) * 8 + j;
        int cc = t * 16 + (lane & 15);
        wp1[i] = f16r(W1[k * 64 + cc]);
        wph[i] = f16r(Wh[k * 64 + cc]);
        if (t < 3) wp2[i] = f16r(cc < 40 ? W2[k * 40 + cc] : 0.f);
    } else {
        int i = (bid - 16) * 256 + threadIdx.x;
        if (i < n4) {
            float4 v = *(const float4*)(x + (size_t)i * 4);
            ushort4 o;
            o.x = f16r(v.x); o.y = f16r(v.y); o.z = f16r(v.z); o.w = f16r(v.w);
            *(ushort4*)(xb + (size_t)i * 4) = o;
        }
    }
}

// ---------------- aggregation: agg[node] = di*( sum dinv[s]*h[s] + di*h[node] ) ----
// One wave per node (100k waves — TLP is king here). lane = edge-slot(3b) x
// channel-oct(3b); uint4 = 8 fp16 channels, 8 edges per wave-instruction, 16
// edges in flight. VALU-lean inner loop:
//   - branchless loads: tail lanes carry dw=0 + valid default address, so no
//     per-load masks/cndmask bundles
//   - 32-bit byte offsets -> saddr+voffset addressing (v_lshl_add_u32)
//   - weights pre-packed to half2 in the prefetch (shfl'd as int), accumulate
//     with v_pk_fma_f16 (2 MACs/inst), reduce with v_pk_add_f16, epilogue
//     pk_mul + store (no converts)

__launch_bounds__(256, 8)
__global__ void agg_kernel(const unsigned short* __restrict__ h, const int* __restrict__ row_ptr,
                           const int* __restrict__ col, const float* __restrict__ dinv,
                           unsigned short* __restrict__ aggout, int n) {
    int tid = threadIdx.x;
    int lane = tid & 63;
    int node = blockIdx.x * 4 + (tid >> 6);
    if (node >= n) return;

    int sub = lane >> 3;                 // edge slot 0..7
    unsigned choff = (lane & 7) * 16u;   // byte offset of channel-oct in 128B row

    int beg = row_ptr[node];
    int deg = row_ptr[node + 1] - beg;
    float di = dinv[node];
    int total = deg + 1;                 // + virtual self edge (weight di)

    half2v a0 = (half2v)0, a1 = (half2v)0, a2 = (half2v)0, a3 = (half2v)0;

    int base = 0;
    while (base < total) {
        int vi = base + lane;
        int idx = node;
        float dw = 0.f;
        if (vi < deg) {
            idx = col[beg + vi];
            dw = dinv[idx];
        } else if (vi == deg) {
            dw = di;                     // self edge
        }
        int dwp = __builtin_bit_cast(int, __builtin_amdgcn_cvt_pkrtz(dw, dw));
        int cnt = min(total - base, 64);
#pragma unroll
        for (int it = 0; it < 4; ++it) {
            int c0 = it * 16;
            if (c0 >= cnt) break;        // wave-uniform
            int e0 = c0 + sub;
            int e1 = c0 + 8 + sub;
            int s0 = __shfl(idx, e0);
            int w0 = __shfl(dwp, e0);    // packed half2 weight (0 for tail slots)
            int s1 = __shfl(idx, e1);
            int w1 = __shfl(dwp, e1);
            uint4 u0 = *(const uint4*)((const char*)h + (((unsigned)s0 << 7) + choff));
            uint4 u1 = *(const uint4*)((const char*)h + (((unsigned)s1 << 7) + choff));
            half2v wv0 = __builtin_bit_cast(half2v, w0);
            half2v wv1 = __builtin_bit_cast(half2v, w1);
            a0 += __builtin_bit_cast(half2v, u0.x) * wv0;   // v_pk_fma_f16
            a1 += __builtin_bit_cast(half2v, u0.y) * wv0;
            a2 += __builtin_bit_cast(half2v, u0.z) * wv0;
            a3 += __builtin_bit_cast(half2v, u0.w) * wv0;
            a0 += __builtin_bit_cast(half2v, u1.x) * wv1;
            a1 += __builtin_bit_cast(half2v, u1.y) * wv1;
            a2 += __builtin_bit_cast(half2v, u1.z) * wv1;
            a3 += __builtin_bit_cast(half2v, u1.w) * wv1;
        }
        base += cnt;
    }
    // reduce the 8 edge slots (lane bits 3,4,5) in packed f16
#pragma unroll
    for (int off = 8; off <= 32; off <<= 1) {
        a0 += __builtin_bit_cast(half2v, __shfl_xor(__builtin_bit_cast(int, a0), off));
        a1 += __builtin_bit_cast(half2v, __shfl_xor(__builtin_bit_cast(int, a1), off));
        a2 += __builtin_bit_cast(half2v, __shfl_xor(__builtin_bit_cast(int, a2), off));
        a3 += __builtin_bit_cast(half2v, __shfl_xor(__builtin_bit_cast(int, a3), off));
    }

    if (sub == 0) {
        half2v dih = __builtin_bit_cast(half2v, __builtin_amdgcn_cvt_pkrtz(di, di));
        a0 *= dih; a1 *= dih; a2 *= dih; a3 *= dih;   // v_pk_mul_f16
        uint4 o;
        o.x = __builtin_bit_cast(unsigned, a0);
        o.y = __builtin_bit_cast(unsigned, a1);
        o.z = __builtin_bit_cast(unsigned, a2);
        o.w = __builtin_bit_cast(unsigned, a3);
        *(uint4*)((char*)aggout + (((unsigned)node << 7) + choff)) = o;
    }
}

// ---------------- MFMA epilogue GEMMs (f16) ----------------
// One wave per 16-node tile. A-frag: A[m=lane&15][k=quad*8+j] -> contiguous
// uint4 from agg buffer. B-frag from pre-packed wp. C/D: col=lane&15,
// row=quad*4+reg. (Rows >= n in the padded A buffer only affect output rows
// >= n, which are never stored.)

__global__ void gemm_relu_kernel(const unsigned short* __restrict__ A,
                                 const unsigned short* __restrict__ wp,
                                 const float* __restrict__ bias,
                                 unsigned short* __restrict__ out, int nTiles, int n) {
    int wv = blockIdx.x * 4 + (threadIdx.x >> 6);
    int lane = threadIdx.x & 63;
    if (wv >= nTiles) return;
    int q = lane >> 4, c = lane & 15;

    half8 bfrag[4][2];
#pragma unroll
    for (int t = 0; t < 4; ++t)
#pragma unroll
        for (int hh = 0; hh < 2; ++hh)
            bfrag[t][hh] = *(const half8*)(wp + t * 1024 + hh * 512 + lane * 8);
    float bs[4];
#pragma unroll
    for (int t = 0; t < 4; ++t) bs[t] = bias[t * 16 + c];

    int nodeBase = wv * 16;
    const unsigned short* arow = A + (size_t)(nodeBase + c) * 64 + q * 8;
    half8 a0 = *(const half8*)(arow);
    half8 a1 = *(const half8*)(arow + 32);

    f32x4 acc[4];
#pragma unroll
    for (int t = 0; t < 4; ++t) {
        f32x4 z = {0.f, 0.f, 0.f, 0.f};
        z = __builtin_amdgcn_mfma_f32_16x16x32_f16(a0, bfrag[t][0], z, 0, 0, 0);
        z = __builtin_amdgcn_mfma_f32_16x16x32_f16(a1, bfrag[t][1], z, 0, 0, 0);
        acc[t] = z;
    }

#pragma unroll
    for (int r = 0; r < 4; ++r) {
        int node = nodeBase + q * 4 + r;
        if (node < n) {
            unsigned short* orow = out + (size_t)node * 64;
#pragma unroll
            for (int t = 0; t < 4; ++t)
                orow[t * 16 + c] = f16r(fmaxf(acc[t][r] + bs[t], 0.f));
        }
    }
}

__global__ void gemm_lsm_kernel(const unsigned short* __restrict__ A,
                                const unsigned short* __restrict__ wp,
                                const float* __restrict__ bias,
                                float* __restrict__ out, int nTiles, int n) {
    int wv = blockIdx.x * 4 + (threadIdx.x >> 6);
    int lane = threadIdx.x & 63;
    if (wv >= nTiles) return;
    int q = lane >> 4, c = lane & 15;
    bool v2ok = (c < 8);   // col 32+c < 40

    half8 bfrag[3][2];
#pragma unroll
    for (int t = 0; t < 3; ++t)
#pragma unroll
        for (int hh = 0; hh < 2; ++hh)
            bfrag[t][hh] = *(const half8*)(wp + t * 1024 + hh * 512 + lane * 8);
    float bs[3];
    bs[0] = bias[c];
    bs[1] = bias[16 + c];
    bs[2] = v2ok ? bias[32 + c] : 0.f;

    int nodeBase = wv * 16;
    const unsigned short* arow = A + (size_t)(nodeBase + c) * 64 + q * 8;
    half8 a0 = *(const half8*)(arow);
    half8 a1 = *(const half8*)(arow + 32);

    f32x4 acc[3];
#pragma unroll
    for (int t = 0; t < 3; ++t) {
        f32x4 z = {0.f, 0.f, 0.f, 0.f};
        z = __builtin_amdgcn_mfma_f32_16x16x32_f16(a0, bfrag[t][0], z, 0, 0, 0);
        z = __builtin_amdgcn_mfma_f32_16x16x32_f16(a1, bfrag[t][1], z, 0, 0, 0);
        acc[t] = z;
    }

#pragma unroll
    for (int r = 0; r < 4; ++r) {
        int node = nodeBase + q * 4 + r;
        if (node < n) {
            float v0 = acc[0][r] + bs[0];
            float v1 = acc[1][r] + bs[1];
            float v2 = v2ok ? (acc[2][r] + bs[2]) : -INFINITY;
            float m = fmaxf(fmaxf(v0, v1), v2);
#pragma unroll
            for (int off = 1; off <= 8; off <<= 1) m = fmaxf(m, __shfl_xor(m, off));
            float s = expf(v0 - m) + expf(v1 - m) + (v2ok ? expf(v2 - m) : 0.f);
#pragma unroll
            for (int off = 1; off <= 8; off <<= 1) s += __shfl_xor(s, off);
            float ls = m + logf(s);
            float* orow = out + (size_t)node * 40;
            orow[c] = v0 - ls;
            orow[16 + c] = v1 - ls;
            if (v2ok) orow[32 + c] = v2 - ls;
        }
    }
}

// ---------------- launch ----------------

extern "C" void kernel_launch(void* const* d_in, const int* in_sizes, int n_in,
                              void* d_out, int out_size, void* d_ws, size_t ws_size,
                              hipStream_t stream) {
    const float* x  = (const float*)d_in[0];
    const int* ei   = (const int*)d_in[1];
    const float* W1 = (const float*)d_in[2];
    const float* b1 = (const float*)d_in[3];
    const float* Wh = (const float*)d_in[4];
    const float* bh = (const float*)d_in[5];
    const float* W2 = (const float*)d_in[6];
    const float* b2 = (const float*)d_in[7];
    float* out = (float*)d_out;

    const int N = in_sizes[0] / 64;
    const int E = in_sizes[1] / 2;
    const int nbuk = (N + 511) >> 9;         // 512-node buckets (needs N <= 131072)
    const int nTiles = (N + 15) / 16;
    const int Npad = nTiles * 16;

    const int* srcp = ei;
    const int* dstp = ei + E;

    size_t off = 0;
    auto alloc = [&](size_t bytes) {
        size_t o = off;
        off = (off + bytes + 255) & ~(size_t)255;
        return o;
    };
    char* ws = (char*)d_ws;
    int*      cntg    = (int*)(ws + alloc(256 * 4));
    int*      row_ptr = (int*)(ws + alloc((size_t)(N + 1) * 4));
    float*    dinv    = (float*)(ws + alloc((size_t)N * 4));
    int*      col     = (int*)(ws + alloc((size_t)E * 4));
    unsigned* ebuf    = (unsigned*)(ws + alloc((size_t)nbuk * BCAP * 4));
    unsigned short* wp1  = (unsigned short*)(ws + alloc(4096 * 2));
    unsigned short* wph  = (unsigned short*)(ws + alloc(4096 * 2));
    unsigned short* wp2  = (unsigned short*)(ws + alloc(3072 * 2));
    unsigned short* xb   = (unsigned short*)(ws + alloc((size_t)Npad * 64 * 2));
    unsigned short* aggA = (unsigned short*)(ws + alloc((size_t)Npad * 64 * 2));
    unsigned short* gA   = (unsigned short*)(ws + alloc((size_t)Npad * 64 * 2));
    (void)ws_size;

    hipMemsetAsync(cntg, 0, 256 * 4, stream);

    const int ebGrid = (E + 256 * EPT - 1) / (256 * EPT);
    scat1_kernel<<<ebGrid, 256, 0, stream>>>(srcp, dstp, cntg, ebuf, E);
    build_kernel<<<nbuk, 256, 0, stream>>>(ebuf, cntg, row_ptr, col, dinv, N, E);

    const int n4 = N * 64 / 4;
    cvtpack_kernel<<<16 + (n4 + 255) / 256, 256, 0, stream>>>(x, xb, n4, W1, Wh, W2, wp1, wph, wp2);

    const int aggGrid = (N + 3) / 4;
    const int gemmGrid = (nTiles + 3) / 4;

    // layer 1
    agg_kernel<<<aggGrid, 256, 0, stream>>>(xb, row_ptr, col, dinv, aggA, N);
    gemm_relu_kernel<<<gemmGrid, 256, 0, stream>>>(aggA, wp1, b1, gA, nTiles, N);
    // layer 2
    agg_kernel<<<aggGrid, 256, 0, stream>>>(gA, row_ptr, col, dinv, aggA, N);
    gemm_relu_kernel<<<gemmGrid, 256, 0, stream>>>(aggA, wph, bh, gA, nTiles, N);
    // layer 3
    agg_kernel<<<aggGrid, 256, 0, stream>>>(gA, row_ptr, col, dinv, aggA, N);
    gemm_lsm_kernel<<<gemmGrid, 256, 0, stream>>>(aggA, wp2, b2, out, nTiles, N);
}

// Round 11
// 267.108 us; speedup vs baseline: 1.1709x; 1.0350x over previous
//
#include <hip/hip_runtime.h>
#include <hip/hip_bf16.h>
#include <math.h>

#define EPT 16      // edges per thread in scatter kernel
#define BCAP 16384  // bucket capacity (avg ~8.2k for uniform random, +90 sigma)

typedef _Float16 half8 __attribute__((ext_vector_type(8)));
typedef _Float16 half2v __attribute__((ext_vector_type(2)));
typedef float f32x4 __attribute__((ext_vector_type(4)));

__device__ __forceinline__ unsigned short f16r(float f) {
    _Float16 h = (_Float16)f;
    return __builtin_bit_cast(unsigned short, h);
}
__device__ __forceinline__ half2v h2(unsigned u) {
    return __builtin_bit_cast(half2v, u);
}

// ---------------- CSR build: single-pass 512-node bucket binning ----------------
// bucket b = dst >> 9; edge record = (src << 9) | (dst & 511)  [needs N <= 131072]
// src/dst cached in registers across the histogram and scatter passes.

__global__ void scat1_kernel(const int* __restrict__ src, const int* __restrict__ dst,
                             int* __restrict__ cntg, unsigned* __restrict__ ebuf, int E) {
    __shared__ int lh[256];
    __shared__ int lbase[256];
    int tid = threadIdx.x;
    lh[tid] = 0;
    __syncthreads();
    int base = blockIdx.x * (256 * EPT);
    int ds[EPT], ss[EPT];
#pragma unroll
    for (int k = 0; k < EPT; ++k) {
        int e = base + k * 256 + tid;
        ds[k] = (e < E) ? dst[e] : -1;
        ss[k] = (e < E) ? src[e] : 0;
    }
#pragma unroll
    for (int k = 0; k < EPT; ++k) {
        if (ds[k] >= 0) atomicAdd(&lh[ds[k] >> 9], 1);
    }
    __syncthreads();
    if (lh[tid] > 0) lbase[tid] = atomicAdd(&cntg[tid], lh[tid]);
    lh[tid] = 0;
    __syncthreads();
#pragma unroll
    for (int k = 0; k < EPT; ++k) {
        if (ds[k] >= 0) {
            int b = ds[k] >> 9;
            int pos = lbase[b] + atomicAdd(&lh[b], 1);
            ebuf[(size_t)b * BCAP + pos] = ((unsigned)ss[k] << 9) | (unsigned)(ds[k] & 511);
        }
    }
}

// one block per bucket: inline scan of bucket counts -> local degrees -> scan
// -> row_ptr/dinv -> fine scatter
__global__ void build_kernel(const unsigned* __restrict__ ebuf, const int* __restrict__ cntg,
                             int* __restrict__ row_ptr, int* __restrict__ col,
                             float* __restrict__ dinv, int N, int E) {
    __shared__ int deg[512];
    __shared__ int sh[256];
    int b = blockIdx.x;
    int tid = threadIdx.x;

    // block-local exclusive scan of the 256 bucket counts to get this bucket's start
    int v = cntg[tid];
    sh[tid] = v;
    __syncthreads();
    int val = v;
    for (int off = 1; off < 256; off <<= 1) {
        int add = 0;
        if (tid >= off) add = sh[tid - off];
        __syncthreads();
        val += add;
        sh[tid] = val;
        __syncthreads();
    }
    int start = (b > 0) ? sh[b - 1] : 0;   // exclusive prefix for bucket b
    int cnt = cntg[b];
    __syncthreads();

    int nodeBase = b << 9;
    int nn = N - nodeBase;
    if (nn > 512) nn = 512;
    if (nn < 0) nn = 0;
    const unsigned* eb = ebuf + (size_t)b * BCAP;

    deg[tid] = 0;
    deg[tid + 256] = 0;
    __syncthreads();
    for (int j = tid; j < cnt; j += 256) {
        atomicAdd(&deg[eb[j] & 511u], 1);
    }
    __syncthreads();

    int i0 = tid * 2, i1 = i0 + 1;
    int v0 = deg[i0], v1 = deg[i1];
    int tot = v0 + v1;
    sh[tid] = tot;
    __syncthreads();
    int val2 = tot;
    for (int off = 1; off < 256; off <<= 1) {
        int add = 0;
        if (tid >= off) add = sh[tid - off];
        __syncthreads();
        val2 += add;
        sh[tid] = val2;
        __syncthreads();
    }
    int excl = val2 - tot;

    if (i0 < nn) { row_ptr[nodeBase + i0] = start + excl;      dinv[nodeBase + i0] = rsqrtf((float)v0 + 1.0f); }
    if (i1 < nn) { row_ptr[nodeBase + i1] = start + excl + v0; dinv[nodeBase + i1] = rsqrtf((float)v1 + 1.0f); }
    if (b == 0 && tid == 0) row_ptr[N] = E;
    // repurpose deg[] as absolute write cursors
    deg[i0] = start + excl;
    deg[i1] = start + excl + v0;
    __syncthreads();

    for (int j = tid; j < cnt; j += 256) {
        unsigned rec = eb[j];
        int pos = atomicAdd(&deg[rec & 511u], 1);
        col[pos] = (int)(rec >> 9);
    }
}

// ---------------- fused convert + weight pack (fp16) ----------------
// blocks [0,16): pack W1/Wh/W2 into MFMA B-fragment order (fp16).
// blocks [16, ...): xb[row] = dinv[row] * x[row]  (pre-scaled features), plus
// block 16 zeroes xb row Npad (the gather zero-row).

__global__ void cvtpack_kernel(const float* __restrict__ x, unsigned short* __restrict__ xb,
                               int n4, int npad, const float* __restrict__ dinv,
                               const float* __restrict__ W1, const float* __restrict__ Wh,
                               const float* __restrict__ W2, unsigned short* __restrict__ wp1,
                               unsigned short* __restrict__ wph, unsigned short* __restrict__ wp2) {
    int bid = blockIdx.x;
    if (bid < 16) {
        int i = bid * 256 + threadIdx.x;   // i in [0,4096)
        int j = i & 7;
        int lane = (i >> 3) & 63;
        int hh = (i >> 9) & 1;
        int t = i >> 10;
        int k = hh * 32 + (lane >> 4) * 8 + j;
        int cc = t * 16 + (lane & 15);
        wp1[i] = f16r(W1[k * 64 + cc]);
        wph[i] = f16r(Wh[k * 64 + cc]);
        if (t < 3) wp2[i] = f16r(cc < 40 ? W2[k * 40 + cc] : 0.f);
    } else {
        if (bid == 16 && threadIdx.x < 8) {
            *(uint4*)(xb + (size_t)npad * 64 + threadIdx.x * 8) = make_uint4(0, 0, 0, 0);
        }
        int i = (bid - 16) * 256 + threadIdx.x;
        if (i < n4) {
            float dn = dinv[i >> 4];
            float4 v = *(const float4*)(x + (size_t)i * 4);
            ushort4 o;
            o.x = f16r(v.x * dn); o.y = f16r(v.y * dn);
            o.z = f16r(v.z * dn); o.w = f16r(v.w * dn);
            *(ushort4*)(xb + (size_t)i * 4) = o;
        }
    }
}

// ---------------- aggregation: agg[node] = di * sum_{j in N(i)+self} h'[j] ----
// h' is producer-pre-scaled (h'[j] = dj*h[j]), so the gather is a pure
// unweighted packed-f16 sum: no weight shfls, no dinv gather, no cndmask.
// Tail lanes index the dedicated zero row (zrow), so loads are branchless and
// dead tail loads hit a hot cached line. One wave per node (TLP is king).

__launch_bounds__(256, 8)
__global__ void agg_kernel(const unsigned short* __restrict__ h, const int* __restrict__ row_ptr,
                           const int* __restrict__ col, const float* __restrict__ dinv,
                           unsigned short* __restrict__ aggout, int n, int zrow) {
    int tid = threadIdx.x;
    int lane = tid & 63;
    int node = blockIdx.x * 4 + (tid >> 6);
    if (node >= n) return;

    int sub = lane >> 3;                 // edge slot 0..7
    unsigned choff = (lane & 7) * 16u;   // byte offset of channel-oct in 128B row

    int beg = row_ptr[node];
    int deg = row_ptr[node + 1] - beg;
    float di = dinv[node];
    int total = deg + 1;                 // + self edge

    half2v a0 = (half2v)0, a1 = (half2v)0, a2 = (half2v)0, a3 = (half2v)0;

    int base = 0;
    while (base < total) {
        int vi = base + lane;
        int idx = zrow;                  // tail -> zero row
        if (vi < deg) idx = col[beg + vi];
        else if (vi == deg) idx = node;  // self edge (h'[node] = dn*h[node])
        int cnt = min(total - base, 64);
#pragma unroll
        for (int it = 0; it < 4; ++it) {
            int c0 = it * 16;
            if (c0 >= cnt) break;        // wave-uniform
            int s0 = __shfl(idx, c0 + sub);
            int s1 = __shfl(idx, c0 + 8 + sub);
            uint4 u0 = *(const uint4*)((const char*)h + (((unsigned)s0 << 7) + choff));
            uint4 u1 = *(const uint4*)((const char*)h + (((unsigned)s1 << 7) + choff));
            a0 += h2(u0.x);  a1 += h2(u0.y);  a2 += h2(u0.z);  a3 += h2(u0.w);
            a0 += h2(u1.x);  a1 += h2(u1.y);  a2 += h2(u1.z);  a3 += h2(u1.w);
        }
        base += cnt;
    }
    // reduce the 8 edge slots (lane bits 3,4,5) in packed f16
#pragma unroll
    for (int off = 8; off <= 32; off <<= 1) {
        a0 += __builtin_bit_cast(half2v, __shfl_xor(__builtin_bit_cast(int, a0), off));
        a1 += __builtin_bit_cast(half2v, __shfl_xor(__builtin_bit_cast(int, a1), off));
        a2 += __builtin_bit_cast(half2v, __shfl_xor(__builtin_bit_cast(int, a2), off));
        a3 += __builtin_bit_cast(half2v, __shfl_xor(__builtin_bit_cast(int, a3), off));
    }

    if (sub == 0) {
        half2v dih = __builtin_bit_cast(half2v, __builtin_amdgcn_cvt_pkrtz(di, di));
        a0 *= dih; a1 *= dih; a2 *= dih; a3 *= dih;   // v_pk_mul_f16
        uint4 o;
        o.x = __builtin_bit_cast(unsigned, a0);
        o.y = __builtin_bit_cast(unsigned, a1);
        o.z = __builtin_bit_cast(unsigned, a2);
        o.w = __builtin_bit_cast(unsigned, a3);
        *(uint4*)((char*)aggout + (((unsigned)node << 7) + choff)) = o;
    }
}

// ---------------- MFMA epilogue GEMMs (f16) ----------------
// gemm_relu stores the NEXT layer's pre-scaled features:
//   out[node] = dinv[node] * relu(A@W + b)
// and zeroes the gather zero-row (row zrow). gemm_lsm stores fp32 log-softmax.

__global__ void gemm_relu_kernel(const unsigned short* __restrict__ A,
                                 const unsigned short* __restrict__ wp,
                                 const float* __restrict__ bias,
                                 const float* __restrict__ dinv,
                                 unsigned short* __restrict__ out, int nTiles, int n, int zrow) {
    if (blockIdx.x == 0 && threadIdx.x < 8) {
        *(uint4*)(out + (size_t)zrow * 64 + threadIdx.x * 8) = make_uint4(0, 0, 0, 0);
    }
    int wv = blockIdx.x * 4 + (threadIdx.x >> 6);
    int lane = threadIdx.x & 63;
    if (wv >= nTiles) return;
    int q = lane >> 4, c = lane & 15;

    half8 bfrag[4][2];
#pragma unroll
    for (int t = 0; t < 4; ++t)
#pragma unroll
        for (int hh = 0; hh < 2; ++hh)
            bfrag[t][hh] = *(const half8*)(wp + t * 1024 + hh * 512 + lane * 8);
    float bs[4];
#pragma unroll
    for (int t = 0; t < 4; ++t) bs[t] = bias[t * 16 + c];

    int nodeBase = wv * 16;
    const unsigned short* arow = A + (size_t)(nodeBase + c) * 64 + q * 8;
    half8 a0 = *(const half8*)(arow);
    half8 a1 = *(const half8*)(arow + 32);

    f32x4 acc[4];
#pragma unroll
    for (int t = 0; t < 4; ++t) {
        f32x4 z = {0.f, 0.f, 0.f, 0.f};
        z = __builtin_amdgcn_mfma_f32_16x16x32_f16(a0, bfrag[t][0], z, 0, 0, 0);
        z = __builtin_amdgcn_mfma_f32_16x16x32_f16(a1, bfrag[t][1], z, 0, 0, 0);
        acc[t] = z;
    }

#pragma unroll
    for (int r = 0; r < 4; ++r) {
        int node = nodeBase + q * 4 + r;
        if (node < n) {
            float dn = dinv[node];
            unsigned short* orow = out + (size_t)node * 64;
#pragma unroll
            for (int t = 0; t < 4; ++t)
                orow[t * 16 + c] = f16r(fmaxf(acc[t][r] + bs[t], 0.f) * dn);
        }
    }
}

__global__ void gemm_lsm_kernel(const unsigned short* __restrict__ A,
                                const unsigned short* __restrict__ wp,
                                const float* __restrict__ bias,
                                float* __restrict__ out, int nTiles, int n) {
    int wv = blockIdx.x * 4 + (threadIdx.x >> 6);
    int lane = threadIdx.x & 63;
    if (wv >= nTiles) return;
    int q = lane >> 4, c = lane & 15;
    bool v2ok = (c < 8);   // col 32+c < 40

    half8 bfrag[3][2];
#pragma unroll
    for (int t = 0; t < 3; ++t)
#pragma unroll
        for (int hh = 0; hh < 2; ++hh)
            bfrag[t][hh] = *(const half8*)(wp + t * 1024 + hh * 512 + lane * 8);
    float bs[3];
    bs[0] = bias[c];
    bs[1] = bias[16 + c];
    bs[2] = v2ok ? bias[32 + c] : 0.f;

    int nodeBase = wv * 16;
    const unsigned short* arow = A + (size_t)(nodeBase + c) * 64 + q * 8;
    half8 a0 = *(const half8*)(arow);
    half8 a1 = *(const half8*)(arow + 32);

    f32x4 acc[3];
#pragma unroll
    for (int t = 0; t < 3; ++t) {
        f32x4 z = {0.f, 0.f, 0.f, 0.f};
        z = __builtin_amdgcn_mfma_f32_16x16x32_f16(a0, bfrag[t][0], z, 0, 0, 0);
        z = __builtin_amdgcn_mfma_f32_16x16x32_f16(a1, bfrag[t][1], z, 0, 0, 0);
        acc[t] = z;
    }

#pragma unroll
    for (int r = 0; r < 4; ++r) {
        int node = nodeBase + q * 4 + r;
        if (node < n) {
            float v0 = acc[0][r] + bs[0];
            float v1 = acc[1][r] + bs[1];
            float v2 = v2ok ? (acc[2][r] + bs[2]) : -INFINITY;
            float m = fmaxf(fmaxf(v0, v1), v2);
#pragma unroll
            for (int off = 1; off <= 8; off <<= 1) m = fmaxf(m, __shfl_xor(m, off));
            float s = expf(v0 - m) + expf(v1 - m) + (v2ok ? expf(v2 - m) : 0.f);
#pragma unroll
            for (int off = 1; off <= 8; off <<= 1) s += __shfl_xor(s, off);
            float ls = m + logf(s);
            float* orow = out + (size_t)node * 40;
            orow[c] = v0 - ls;
            orow[16 + c] = v1 - ls;
            if (v2ok) orow[32 + c] = v2 - ls;
        }
    }
}

// ---------------- launch ----------------

extern "C" void kernel_launch(void* const* d_in, const int* in_sizes, int n_in,
                              void* d_out, int out_size, void* d_ws, size_t ws_size,
                              hipStream_t stream) {
    const float* x  = (const float*)d_in[0];
    const int* ei   = (const int*)d_in[1];
    const float* W1 = (const float*)d_in[2];
    const float* b1 = (const float*)d_in[3];
    const float* Wh = (const float*)d_in[4];
    const float* bh = (const float*)d_in[5];
    const float* W2 = (const float*)d_in[6];
    const float* b2 = (const float*)d_in[7];
    float* out = (float*)d_out;

    const int N = in_sizes[0] / 64;
    const int E = in_sizes[1] / 2;
    const int nbuk = (N + 511) >> 9;         // 512-node buckets (needs N <= 131072)
    const int nTiles = (N + 15) / 16;
    const int Npad = nTiles * 16;            // zero-row index; buffers have Npad+1 rows

    const int* srcp = ei;
    const int* dstp = ei + E;

    size_t off = 0;
    auto alloc = [&](size_t bytes) {
        size_t o = off;
        off = (off + bytes + 255) & ~(size_t)255;
        return o;
    };
    char* ws = (char*)d_ws;
    int*      cntg    = (int*)(ws + alloc(256 * 4));
    int*      row_ptr = (int*)(ws + alloc((size_t)(N + 1) * 4));
    float*    dinv    = (float*)(ws + alloc((size_t)N * 4));
    int*      col     = (int*)(ws + alloc((size_t)E * 4));
    unsigned* ebuf    = (unsigned*)(ws + alloc((size_t)nbuk * BCAP * 4));
    unsigned short* wp1  = (unsigned short*)(ws + alloc(4096 * 2));
    unsigned short* wph  = (unsigned short*)(ws + alloc(4096 * 2));
    unsigned short* wp2  = (unsigned short*)(ws + alloc(3072 * 2));
    unsigned short* xb   = (unsigned short*)(ws + alloc((size_t)(Npad + 1) * 64 * 2));
    unsigned short* aggA = (unsigned short*)(ws + alloc((size_t)Npad * 64 * 2));
    unsigned short* gA   = (unsigned short*)(ws + alloc((size_t)(Npad + 1) * 64 * 2));
    (void)ws_size;

    hipMemsetAsync(cntg, 0, 256 * 4, stream);

    const int ebGrid = (E + 256 * EPT - 1) / (256 * EPT);
    scat1_kernel<<<ebGrid, 256, 0, stream>>>(srcp, dstp, cntg, ebuf, E);
    build_kernel<<<nbuk, 256, 0, stream>>>(ebuf, cntg, row_ptr, col, dinv, N, E);

    const int n4 = N * 16;   // float4 groups (16 per 64-ch row)
    cvtpack_kernel<<<16 + (n4 + 255) / 256, 256, 0, stream>>>(x, xb, n4, Npad, dinv,
                                                              W1, Wh, W2, wp1, wph, wp2);

    const int aggGrid = (N + 3) / 4;
    const int gemmGrid = (nTiles + 3) / 4;

    // layer 1
    agg_kernel<<<aggGrid, 256, 0, stream>>>(xb, row_ptr, col, dinv, aggA, N, Npad);
    gemm_relu_kernel<<<gemmGrid, 256, 0, stream>>>(aggA, wp1, b1, dinv, gA, nTiles, N, Npad);
    // layer 2
    agg_kernel<<<aggGrid, 256, 0, stream>>>(gA, row_ptr, col, dinv, aggA, N, Npad);
    gemm_relu_kernel<<<gemmGrid, 256, 0, stream>>>(aggA, wph, bh, dinv, gA, nTiles, N, Npad);
    // layer 3
    agg_kernel<<<aggGrid, 256, 0, stream>>>(gA, row_ptr, col, dinv, aggA, N, Npad);
    gemm_lsm_kernel<<<gemmGrid, 256, 0, stream>>>(aggA, wp2, b2, out, nTiles, N);
}